// Round 5
// baseline (470.885 us; speedup 1.0000x reference)
//
#include <hip/hip_runtime.h>
#include <stdint.h>

// ---------------------------------------------------------------------------
// Problem constants
// ---------------------------------------------------------------------------
#define BB    4096
#define DD    1024
#define TT    768
#define CC    16
#define HH    4
#define SS    4
#define HD    256
#define M1    (BB*SS)     // 16384 rows
#define CURVF 0.05f
#define SCF   0.22360679774997896f   // sqrt(0.05)
#define EPSF  1e-8f
#define ASINH_MAXF 11.090354888959125f  // asinh(2^15)

// d_out element offsets: [logits B*C][loss 1][oh B*D][fh B*D][oeu B*D][feu B*D]
#define OFF_LOGITS 0ull
#define OFF_LOSS   65536ull
#define OFF_OH     65537ull
#define OFF_FH     (65537ull + 4194304ull)
#define OFF_OEU    (65537ull + 2ull*4194304ull)
#define OFF_FEU    (65537ull + 3ull*4194304ull)

typedef __attribute__((ext_vector_type(8))) short bf16x8;
typedef __attribute__((ext_vector_type(4))) float f32x4;

__device__ __forceinline__ float bf2f(unsigned short h) {
  union { unsigned int u; float f; } v; v.u = ((unsigned int)h) << 16; return v.f;
}
__device__ __forceinline__ unsigned short f2bf(float f) {
  union { float f; unsigned int u; } v; v.f = f;
  unsigned int u = v.u;
  return (unsigned short)((u + 0x7FFFu + ((u >> 16) & 1u)) >> 16);
}
__device__ __forceinline__ ushort4 f2bf4(float4 v) {
  ushort4 o; o.x = f2bf(v.x); o.y = f2bf(v.y); o.z = f2bf(v.z); o.w = f2bf(v.w);
  return o;
}
__device__ __forceinline__ float wsum(float v) {
#pragma unroll
  for (int o = 32; o > 0; o >>= 1) v += __shfl_xor(v, o, 64);
  return v;
}
__device__ __forceinline__ float block_sum(float v, float* red) {
  v = wsum(v);
  int lane = threadIdx.x & 63, wv = threadIdx.x >> 6;
  __syncthreads();
  if (lane == 0) red[wv] = v;
  __syncthreads();
  return red[0] + red[1] + red[2] + red[3];
}
__device__ __forceinline__ float artanh_clip(float x) {
  x = fminf(fmaxf(x, -1.0f + 1e-5f), 1.0f - 1e-5f);
  return 0.5f * (log1pf(x) - log1pf(-x));
}

typedef __attribute__((address_space(1))) const void gas_void;
typedef __attribute__((address_space(3))) void las_void;
__device__ __forceinline__ void gld16(void* l, const void* g) {
  __builtin_amdgcn_global_load_lds((gas_void*)g, (las_void*)l, 16, 0, 0);
}

#define VMCNT(n) asm volatile("s_waitcnt vmcnt(" #n ")" ::: "memory")
#define BARRIER() do { asm volatile("" ::: "memory"); __builtin_amdgcn_s_barrier(); asm volatile("" ::: "memory"); } while (0)
#define LGKM0() do { asm volatile("s_waitcnt lgkmcnt(0)" ::: "memory"); __builtin_amdgcn_sched_barrier(0); } while (0)

// ---------------------------------------------------------------------------
// merged fp32 -> bf16 convert over 6 segments (float4-wide)
// ---------------------------------------------------------------------------
struct Cvt6 {
  const float4* src[6];
  unsigned short* dst[6];
  unsigned int end4[6];   // cumulative float4 counts
};
__global__ __launch_bounds__(256) void k_cvt6(Cvt6 c, unsigned int total4) {
  unsigned int i = blockIdx.x * 256 + threadIdx.x;
  if (i >= total4) return;
#pragma unroll
  for (int j = 0; j < 6; j++) {
    if (i < c.end4[j]) {
      unsigned int k = i - (j ? c.end4[j - 1] : 0u);
      ((ushort4*)c.dst[j])[k] = f2bf4(c.src[j][k]);
      return;
    }
  }
}

// ---------------------------------------------------------------------------
// gf = stack([p_logmap0(order_hyp), p_logmap0(family_hyp), order_euc, family_euc])
// ---------------------------------------------------------------------------
__global__ __launch_bounds__(256) void k_prep_gf(const float* __restrict__ ohyp,
    const float* __restrict__ fhyp, const float* __restrict__ oeuc,
    const float* __restrict__ feuc, unsigned short* __restrict__ gf) {
  __shared__ float red[4];
  int b = blockIdx.x;
  int t = threadIdx.x;
  size_t base4 = (size_t)b * (DD / 4);
  float4 xo = ((const float4*)ohyp)[base4 + t];
  float4 xf = ((const float4*)fhyp)[base4 + t];
  float so = xo.x * xo.x + xo.y * xo.y + xo.z * xo.z + xo.w * xo.w;
  float sf = xf.x * xf.x + xf.y * xf.y + xf.z * xf.z + xf.w * xf.w;
  float no2 = block_sum(so, red);
  float nf2 = block_sum(sf, red);
  float no = fmaxf(sqrtf(no2), 1e-15f);
  float nf = fmaxf(sqrtf(nf2), 1e-15f);
  float fo = artanh_clip(SCF * no) / (no * SCF);
  float ff = artanh_clip(SCF * nf) / (nf * SCF);
  size_t g0 = (size_t)b * 4 * (DD / 4);
  float4 e2 = ((const float4*)oeuc)[base4 + t];
  float4 e3 = ((const float4*)feuc)[base4 + t];
  float4 y0 = {xo.x * fo, xo.y * fo, xo.z * fo, xo.w * fo};
  float4 y1 = {xf.x * ff, xf.y * ff, xf.z * ff, xf.w * ff};
  ((ushort4*)gf)[g0 + t]              = f2bf4(y0);
  ((ushort4*)gf)[g0 + DD / 4 + t]     = f2bf4(y1);
  ((ushort4*)gf)[g0 + 2 * DD / 4 + t] = f2bf4(e2);
  ((ushort4*)gf)[g0 + 3 * DD / 4 + t] = f2bf4(e3);
}

// ---------------------------------------------------------------------------
// 256x256-tile bf16 GEMM, C = A(MxK) * Bm(NxK)^T + bias — 8-phase schedule
// (T2+T3+T4+T5 per the 256² template; m218: counted-vmcnt gain REQUIRES the
// fine phase interleave — R3's coarse 2-phase stalled at 874 TF / 38% MfmaUtil).
//
// Geometry: BK=64, 8 waves (2M x 4N), per-wave output 128x64.
// LDS: [2 dbuf][2 half][128][64] per operand = 64KB A + 64KB B = 128 KiB.
// Per K-tile: 4 phases, each = {ds_read frags | stage half-tile -> barrier ->
// lgkmcnt(0)+sched_barrier -> setprio(1) -> 16 MFMA -> setprio(0) -> barrier}.
//   P1 (ih0,jh0): read A(ih0)[8] + B(jh0)[4]; stage B-lo(T+1)
//   P2 (ih0,jh1): read B(jh1)[4];             stage B-hi(T+1)
//   P3 (ih1,jh1): read A(ih1)[8]
//   P4 (ih1,jh0): (frags live);               stage A(T+2) [4], vmcnt(4)
// vmcnt accounting (FIFO, per wave): at P4(T) outstanding = A(T+1)[4] +
// Blo(T+1)[2] + Bhi(T+1)[2] + A(T+2)[4]; vmcnt(4) forces all of tile T+1
// landed (what P1(T+1) reads) and lets A(T+2) fly -> counted, never 0.
// Race safety: stage into a buffer only after the barrier-B of the phase
// holding the last ds_read of that buffer (every wave's lgkmcnt(0) precedes
// its barrier-B) — A-buf last read P3, staged P4; B-buf last read P2(T),
// staged P1/P2(T+1).
// Swizzle (T2): LDS row stride = 128B = all 32 banks; store global chunk
// (c ^ (row&7)) at LDS chunk c via pre-swizzled SOURCE column (linear
// global_load_lds dest, rule 21). Read back with the same XOR (key = fr&7,
// per-lane constant). Result: each 16-lane group hits 8 bank-quads x 2 =
// 2-way (free, m136).
// ---------------------------------------------------------------------------
template <int OUT_BF16>
__global__ __launch_bounds__(512, 2) void k_gemm256(
    const unsigned short* __restrict__ A, const unsigned short* __restrict__ Bm,
    const float* __restrict__ bias, void* __restrict__ Cv,
    int N, int K, int nx) {
  __shared__ unsigned short As[2 * 2 * 128 * 64];   // 64 KB
  __shared__ unsigned short Bs[2 * 2 * 128 * 64];   // 64 KB
  const int nwg = gridDim.x;
  const int rid = blockIdx.x;
  const int wg = (rid & 7) * (nwg >> 3) + (rid >> 3);  // XCD-contiguous (nwg%8==0)
  const int bx = wg % nx;
  const int by = wg / nx;
  const long tileM = (long)by * 256;
  const long tileN = (long)bx * 256;
  const int tid = threadIdx.x;
  const int lane = tid & 63;
  const int wv = tid >> 6;       // 0..7
  const int wr = wv >> 2;        // 0..1  (M half)
  const int wc = wv & 3;         // 0..3  (N quarter)
  const int NT = K >> 6;         // K-tiles of 64 (K=1024 -> 16)

  f32x4 acc[8][4];
#pragma unroll
  for (int i = 0; i < 8; i++)
#pragma unroll
    for (int j = 0; j < 4; j++) acc[i][j] = (f32x4){0.f, 0.f, 0.f, 0.f};

  // ---- staging geometry: thread covers (row = tid>>3, chunk = tid&7) of a
  // 64-row slab; dest = base + tid*16B (linear, as global_load_lds needs);
  // source column pre-swizzled so LDS(row,chunk) = global(row, chunk^(row&7)).
  const int srow = tid >> 3;                    // 0..63
  const int sc = (tid & 7) ^ (srow & 7);        // pre-swizzled source chunk
  const unsigned short* Ag = A + (tileM + srow) * (long)K + sc * 8;
  const unsigned short* Bg = Bm + (tileN + srow) * (long)K + sc * 8;

#define STAGE_A(T_) do { \
    unsigned short* d_ = As + ((T_) & 1) * 16384; \
    const unsigned short* g_ = Ag + (long)(T_) * 64; \
    gld16(d_ + tid * 8,          g_); \
    gld16(d_ + 4096 + tid * 8,   g_ + (long)64 * K); \
    gld16(d_ + 8192 + tid * 8,   g_ + (long)128 * K); \
    gld16(d_ + 12288 + tid * 8,  g_ + (long)192 * K); } while (0)
#define STAGE_BLO(T_) do { \
    unsigned short* d_ = Bs + ((T_) & 1) * 16384; \
    const unsigned short* g_ = Bg + (long)(T_) * 64; \
    gld16(d_ + tid * 8,          g_); \
    gld16(d_ + 4096 + tid * 8,   g_ + (long)64 * K); } while (0)
#define STAGE_BHI(T_) do { \
    unsigned short* d_ = Bs + ((T_) & 1) * 16384 + 8192; \
    const unsigned short* g_ = Bg + (long)(T_) * 64 + (long)128 * K; \
    gld16(d_ + tid * 8,          g_); \
    gld16(d_ + 4096 + tid * 8,   g_ + (long)64 * K); } while (0)

  // ---- fragment read bases (byte-swizzled chunk = c ^ (fr&7))
  const int fr = lane & 15;
  const int hi = lane >> 4;
  const int fx = fr & 7;
  const unsigned short* ArdBase = As + wr * 8192 + fr * 64;
  const unsigned short* BrdBase = Bs + (wc >> 1) * 8192 + (wc & 1) * 4096 + fr * 64;

#define LDA8(dst_, p_, ihsel_) do { \
    const unsigned short* b_ = ArdBase + (p_) * 16384 + (ihsel_) * 4096; \
    _Pragma("unroll") for (int i2_ = 0; i2_ < 4; i2_++) \
    _Pragma("unroll") for (int s_ = 0; s_ < 2; s_++) \
      dst_[i2_][s_] = *(const bf16x8*)(b_ + i2_ * 1024 + ((s_ * 4 + hi) ^ fx) * 8); } while (0)
#define LDB4(dst_, p_, jhsel_) do { \
    const unsigned short* b_ = BrdBase + (p_) * 16384 + (jhsel_) * 2048; \
    _Pragma("unroll") for (int j2_ = 0; j2_ < 2; j2_++) \
    _Pragma("unroll") for (int s_ = 0; s_ < 2; s_++) \
      dst_[j2_][s_] = *(const bf16x8*)(b_ + j2_ * 1024 + ((s_ * 4 + hi) ^ fx) * 8); } while (0)
#define MFMA16(ihsel_, jhsel_, a_, b_) do { \
    __builtin_amdgcn_s_setprio(1); \
    _Pragma("unroll") for (int i2_ = 0; i2_ < 4; i2_++) \
    _Pragma("unroll") for (int j2_ = 0; j2_ < 2; j2_++) { \
      acc[(ihsel_)*4 + i2_][(jhsel_)*2 + j2_] = __builtin_amdgcn_mfma_f32_16x16x32_bf16( \
          a_[i2_][0], b_[j2_][0], acc[(ihsel_)*4 + i2_][(jhsel_)*2 + j2_], 0, 0, 0); \
      acc[(ihsel_)*4 + i2_][(jhsel_)*2 + j2_] = __builtin_amdgcn_mfma_f32_16x16x32_bf16( \
          a_[i2_][1], b_[j2_][1], acc[(ihsel_)*4 + i2_][(jhsel_)*2 + j2_], 0, 0, 0); \
    } \
    __builtin_amdgcn_s_setprio(0); } while (0)

  // ---- prologue: tile 0 fully staged + A(1); vmcnt(4) lets A(1) fly.
  STAGE_A(0); STAGE_BLO(0); STAGE_BHI(0); STAGE_A(1);
  VMCNT(4);
  BARRIER();

  bf16x8 a_[4][2], b0_[2][2], b1_[2][2];
  for (int T = 0; T < NT; ++T) {
    const int p = T & 1;
    // ---- P1: (ih0, jh0)
    LDA8(a_, p, 0);
    LDB4(b0_, p, 0);
    if (T + 1 < NT) STAGE_BLO(T + 1);
    BARRIER();
    LGKM0();
    MFMA16(0, 0, a_, b0_);
    BARRIER();
    // ---- P2: (ih0, jh1)
    LDB4(b1_, p, 1);
    if (T + 1 < NT) STAGE_BHI(T + 1);
    BARRIER();
    LGKM0();
    MFMA16(0, 1, a_, b1_);
    BARRIER();
    // ---- P3: (ih1, jh1)
    LDA8(a_, p, 1);
    BARRIER();
    LGKM0();
    MFMA16(1, 1, a_, b1_);
    BARRIER();
    // ---- P4: (ih1, jh0) — stage A(T+2), counted vmcnt
    if (T + 2 < NT) { STAGE_A(T + 2); VMCNT(4); }
    else            { VMCNT(0); }
    BARRIER();
    MFMA16(1, 0, a_, b0_);
    BARRIER();
  }

#undef STAGE_A
#undef STAGE_BLO
#undef STAGE_BHI
#undef LDA8
#undef LDB4
#undef MFMA16

  // epilogue (C/D mapping: col = lane&15, row = (lane>>4)*4 + reg)
  const int er = hi * 4;
#pragma unroll
  for (int i = 0; i < 8; i++) {
#pragma unroll
    for (int j = 0; j < 4; j++) {
      long col = tileN + wc * 64 + j * 16 + fr;
      float bv = bias ? bias[col] : 0.f;
#pragma unroll
      for (int r = 0; r < 4; r++) {
        long row = tileM + wr * 128 + i * 16 + er + r;
        float v = acc[i][j][r] + bv;
        if (OUT_BF16) ((unsigned short*)Cv)[row * (long)N + col] = f2bf(v);
        else          ((float*)Cv)[row * (long)N + col] = v;
      }
    }
  }
}

// ---------------------------------------------------------------------------
// bf16 GEMM body (128x128 tile, 4 waves) — kept for the small loss GEMMs
// where a 256² grid would underfill the GPU (128 blocks).
// ---------------------------------------------------------------------------
template <int OUT_BF16>
__device__ __forceinline__ void gemm_body(
    unsigned short* As, unsigned short* Bs,
    const unsigned short* __restrict__ A, const unsigned short* __restrict__ Bm,
    const float* __restrict__ bias, void* __restrict__ Cv,
    int M, int N, int K, int bx, int by) {
  const int tid = threadIdx.x;
  const int lane = tid & 63;
  const int wv = tid >> 6;
  const long tileM = (long)by * 128;
  const long tileN = (long)bx * 128;

  f32x4 acc[4][4];
#pragma unroll
  for (int i = 0; i < 4; i++)
#pragma unroll
    for (int j = 0; j < 4; j++) acc[i][j] = (f32x4){0.f, 0.f, 0.f, 0.f};

  const int srow = wv * 16 + (lane >> 2);
  const int lc = (lane & 3) ^ ((srow >> 1) & 3);
  const unsigned short* Ag = A + (tileM + srow) * (long)K + lc * 8;
  const unsigned short* Bg = Bm + (tileN + srow) * (long)K + lc * 8;
  unsigned short* Asl = As + srow * 32 + (lane & 3) * 8;
  unsigned short* Bsl = Bs + srow * 32 + (lane & 3) * 8;

  const int fr = lane & 15;
  const int rkey = (fr >> 1) & 3;
  const int fko2 = (((lane >> 4) ^ rkey)) * 8;
  const int wr = (wv >> 1) * 64;
  const int wc = (wv & 1) * 64;

  for (int k0 = 0; k0 < K; k0 += 32) {
    gld16(Asl, Ag + k0);
    gld16(Asl + 64 * 32, Ag + (long)64 * K + k0);
    gld16(Bsl, Bg + k0);
    gld16(Bsl + 64 * 32, Bg + (long)64 * K + k0);
    __syncthreads();
    bf16x8 af[4], bfr[4];
#pragma unroll
    for (int i = 0; i < 4; i++)
      af[i] = *(const bf16x8*)(As + (wr + i * 16 + fr) * 32 + fko2);
#pragma unroll
    for (int j = 0; j < 4; j++)
      bfr[j] = *(const bf16x8*)(Bs + (wc + j * 16 + fr) * 32 + fko2);
#pragma unroll
    for (int i = 0; i < 4; i++)
#pragma unroll
      for (int j = 0; j < 4; j++)
        acc[i][j] = __builtin_amdgcn_mfma_f32_16x16x32_bf16(af[i], bfr[j], acc[i][j], 0, 0, 0);
    __syncthreads();
  }

  const int er = (lane >> 4) * 4;
  const int ec = lane & 15;
#pragma unroll
  for (int i = 0; i < 4; i++) {
#pragma unroll
    for (int j = 0; j < 4; j++) {
      long col = tileN + wc + j * 16 + ec;
      float bv = bias ? bias[col] : 0.f;
#pragma unroll
      for (int r = 0; r < 4; r++) {
        long row = tileM + wr + i * 16 + er + r;
        float v = acc[i][j][r] + bv;
        if (OUT_BF16) ((unsigned short*)Cv)[row * (long)N + col] = f2bf(v);
        else          ((float*)Cv)[row * (long)N + col] = v;
      }
    }
  }
}

__global__ __launch_bounds__(256) void k_gemm_loss(
    const unsigned short* __restrict__ A0, const unsigned short* __restrict__ B0,
    const float* __restrict__ b0, float* __restrict__ C0,
    const unsigned short* __restrict__ A1, const unsigned short* __restrict__ B1,
    const float* __restrict__ b1, float* __restrict__ C1, int M, int N, int K) {
  __shared__ unsigned short As[128 * 32];
  __shared__ unsigned short Bs[128 * 32];
  if (blockIdx.z == 0)
    gemm_body<0>(As, Bs, A0, B0, b0, C0, M, N, K, blockIdx.x, blockIdx.y);
  else
    gemm_body<0>(As, Bs, A1, B1, b1, C1, M, N, K, blockIdx.x, blockIdx.y);
}

// ---------------------------------------------------------------------------
// tiny attention: S=4, one block per (b,h); wave qi handles query qi.
// ---------------------------------------------------------------------------
__global__ __launch_bounds__(256) void k_attn(const unsigned short* __restrict__ qkv,
                                              unsigned short* __restrict__ o) {
  int b = blockIdx.x;
  int h = blockIdx.y;
  int lane = threadIdx.x & 63;
  int qi = threadIdx.x >> 6;
  const unsigned short* base = qkv + (size_t)b * 4 * 3072 + h * HD;
  int d = lane * 4;
  float qv[4], kv[4][4], vv[4][4];
  {
    ushort4 q4 = *(const ushort4*)(base + (size_t)qi * 3072 + d);
    qv[0] = bf2f(q4.x); qv[1] = bf2f(q4.y); qv[2] = bf2f(q4.z); qv[3] = bf2f(q4.w);
  }
#pragma unroll
  for (int j = 0; j < 4; j++) {
    ushort4 k4 = *(const ushort4*)(base + (size_t)j * 3072 + 1024 + d);
    ushort4 v4 = *(const ushort4*)(base + (size_t)j * 3072 + 2048 + d);
    kv[j][0] = bf2f(k4.x); kv[j][1] = bf2f(k4.y); kv[j][2] = bf2f(k4.z); kv[j][3] = bf2f(k4.w);
    vv[j][0] = bf2f(v4.x); vv[j][1] = bf2f(v4.y); vv[j][2] = bf2f(v4.z); vv[j][3] = bf2f(v4.w);
  }
  float sc_[4];
#pragma unroll
  for (int j = 0; j < 4; j++) {
    float p = 0.f;
#pragma unroll
    for (int t = 0; t < 4; t++) p += qv[t] * kv[j][t];
    sc_[j] = wsum(p) * (1.0f / 16.0f);
  }
  float mx = fmaxf(fmaxf(sc_[0], sc_[1]), fmaxf(sc_[2], sc_[3]));
  float e[4], den = 0.f;
#pragma unroll
  for (int j = 0; j < 4; j++) { e[j] = expf(sc_[j] - mx); den += e[j]; }
  float inv = 1.0f / den;
  float4 ov = {0.f, 0.f, 0.f, 0.f};
#pragma unroll
  for (int j = 0; j < 4; j++) {
    float w = e[j] * inv;
    ov.x += w * vv[j][0]; ov.y += w * vv[j][1];
    ov.z += w * vv[j][2]; ov.w += w * vv[j][3];
  }
  *(ushort4*)(o + (size_t)(b * 4 + qi) * DD + h * HD + d) = f2bf4(ov);
}

// ---------------------------------------------------------------------------
// layernorm(gf + attn) then split; s<2 additionally l_expmap0.
// ---------------------------------------------------------------------------
__global__ __launch_bounds__(256) void k_ln_split(const unsigned short* __restrict__ gf,
    const unsigned short* __restrict__ attn, const float* __restrict__ lnw,
    const float* __restrict__ lnb, float* __restrict__ dout) {
  __shared__ float red[4];
  int r = blockIdx.x;
  int b = r >> 2, s = r & 3;
  int t = threadIdx.x;
  size_t base4 = (size_t)r * (DD / 4);
  ushort4 g4 = ((const ushort4*)gf)[base4 + t];
  ushort4 a4 = ((const ushort4*)attn)[base4 + t];
  float x[4] = {bf2f(g4.x) + bf2f(a4.x), bf2f(g4.y) + bf2f(a4.y),
                bf2f(g4.z) + bf2f(a4.z), bf2f(g4.w) + bf2f(a4.w)};
  float sum = x[0] + x[1] + x[2] + x[3];
  float sq = x[0] * x[0] + x[1] * x[1] + x[2] * x[2] + x[3] * x[3];
  sum = block_sum(sum, red);
  sq  = block_sum(sq, red);
  float mu = sum * (1.0f / (float)DD);
  float var = sq * (1.0f / (float)DD) - mu * mu;
  float inv = rsqrtf(var + 1e-5f);
  float4 w4 = ((const float4*)lnw)[t];
  float4 b4 = ((const float4*)lnb)[t];
  float y[4];
  y[0] = (x[0] - mu) * inv * w4.x + b4.x;
  y[1] = (x[1] - mu) * inv * w4.y + b4.y;
  y[2] = (x[2] - mu) * inv * w4.z + b4.z;
  y[3] = (x[3] - mu) * inv * w4.w + b4.w;
  float fmul = 1.0f;
  if (s < 2) {
    float n2 = y[0] * y[0] + y[1] * y[1] + y[2] * y[2] + y[3] * y[3];
    n2 = block_sum(n2, red);
    float rc = SCF * sqrtf(n2);
    float si = fminf(fmaxf(rc, EPSF), ASINH_MAXF);
    fmul = sinhf(si) / fmaxf(rc, EPSF);
  }
  size_t offs = (s == 0) ? OFF_OH : (s == 1) ? OFF_FH : (s == 2) ? OFF_OEU : OFF_FEU;
  float4* outp = (float4*)(dout + offs + (size_t)b * DD);
  float4 o4 = {y[0] * fmul, y[1] * fmul, y[2] * fmul, y[3] * fmul};
  outp[t] = o4;
}

// ---------------------------------------------------------------------------
// cone loss: per row b, pen -> pens[which*BB + b]. NO atomics.
// ---------------------------------------------------------------------------
__global__ __launch_bounds__(256) void k_oxy(const float* __restrict__ raw0,
    const float* __restrict__ y0, const float* __restrict__ raw1,
    const float* __restrict__ y1, float* __restrict__ pens) {
  __shared__ float red[4];
  int b = blockIdx.x;
  int which = blockIdx.y;
  const float* raw = which ? raw1 : raw0;
  const float* yr  = which ? y1 : y0;
  size_t base = (size_t)b * DD;
  float sxx = 0.f, sxy = 0.f, syy = 0.f;
#pragma unroll
  for (int k = 0; k < 4; k++) {
    int d = threadIdx.x + 256 * k;
    float xv = raw[base + d];
    float yv = yr[base + d];
    sxx += xv * xv; sxy += xv * yv; syy += yv * yv;
  }
  sxx = block_sum(sxx, red);
  sxy = block_sum(sxy, red);
  syy = block_sum(syy, red);
  if (threadIdx.x == 0) {
    float nraw = sqrtf(sxx);
    float rc = SCF * nraw;
    float si = fminf(fmaxf(rc, EPSF), ASINH_MAXF);
    float f = sinhf(si) / fmaxf(rc, EPSF);
    float x2 = f * f * sxx;
    float xy = f * sxy;
    float y2 = syy;
    float nx = f * nraw;
    float xt = sqrtf(1.0f / CURVF + x2);
    float yt = sqrtf(1.0f / CURVF + y2);
    float c_xyl = CURVF * (xy - xt * yt);
    float num = yt + c_xyl * xt;
    float den = sqrtf(fmaxf(c_xyl * c_xyl - 1.0f, EPSF));
    float ai = num / (nx * den + EPSF);
    ai = fminf(fmaxf(ai, -1.0f + EPSF), 1.0f - EPSF);
    float ang = acosf(ai);
    float asi = 0.2f / (nx * SCF + EPSF);
    asi = fminf(fmaxf(asi, -1.0f + EPSF), 1.0f - EPSF);
    float ap = asinf(asi);
    pens[(size_t)which * BB + b] = fmaxf(ang - ap, 0.0f);
  }
}

// single-block reduction of pens + mask -> loss scalar
__global__ __launch_bounds__(256) void k_finalize_loss(const float* __restrict__ pens,
    const int* __restrict__ mask, float* __restrict__ dout) {
  __shared__ float red[4];
  float s0 = 0.f, s1 = 0.f, cnt = 0.f;
  for (int i = threadIdx.x; i < BB; i += 256) {
    s0 += pens[i];
    float m = (float)mask[i];
    s1 += pens[BB + i] * m;
    cnt += m;
  }
  s0 = block_sum(s0, red);
  s1 = block_sum(s1, red);
  cnt = block_sum(cnt, red);
  if (threadIdx.x == 0) {
    float order_loss = s0 / (float)BB;
    float fam = (cnt > 0.f) ? s1 / fmaxf(cnt, 1.0f) : 0.0f;
    dout[OFF_LOSS] = order_loss + fam;
  }
}

// ---------------------------------------------------------------------------
// MLR precompute: cs[c] = {x2, conf, a_norm, kk, xa}
// ---------------------------------------------------------------------------
__global__ __launch_bounds__(256) void k_mlr_prep(const float* __restrict__ a,
    const float* __restrict__ p, float* __restrict__ p_p, float* __restrict__ a_p,
    float* __restrict__ cs) {
  __shared__ float red[4];
  int c = blockIdx.x;
  int t = threadIdx.x;
  size_t base4 = (size_t)c * (DD / 4);
  float4 pv = ((const float4*)p)[base4 + t];
  float4 av = ((const float4*)a)[base4 + t];
  float sp = pv.x * pv.x + pv.y * pv.y + pv.z * pv.z + pv.w * pv.w;
  float sa = av.x * av.x + av.y * av.y + av.z * av.z + av.w * av.w;
  float spa = pv.x * av.x + pv.y * av.y + pv.z * av.z + pv.w * av.w;
  sp = block_sum(sp, red); sa = block_sum(sa, red); spa = block_sum(spa, red);
  float n = fmaxf(sqrtf(sp), 1e-15f);
  float f = tanhf(SCF * n) / (SCF * n);
  float x2 = f * f * sp;
  float conf = 1.0f - CURVF * x2;
  float a_norm = fabsf(conf) * sqrtf(sa);
  float lam = 2.0f / (1.0f - CURVF * x2);
  float kk = lam * a_norm / SCF;
  float xa = -f * conf * spa;
  float4 pp = {pv.x * f, pv.y * f, pv.z * f, pv.w * f};
  float4 ap = {av.x * conf, av.y * conf, av.z * conf, av.w * conf};
  ((float4*)p_p)[base4 + t] = pp;
  ((float4*)a_p)[base4 + t] = ap;
  if (threadIdx.x == 0) {
    cs[c * 5 + 0] = x2; cs[c * 5 + 1] = conf; cs[c * 5 + 2] = a_norm;
    cs[c * 5 + 3] = kk; cs[c * 5 + 4] = xa;
  }
}

// ---------------------------------------------------------------------------
// MLR logits.
// ---------------------------------------------------------------------------
__global__ __launch_bounds__(256) void k_mlr_logits(const float* __restrict__ oh,
    const float* __restrict__ p_p, const float* __restrict__ a_p,
    const float* __restrict__ cs, float* __restrict__ logits) {
  __shared__ float row[DD];
  __shared__ float dots[CC][2];
  __shared__ float s_n2;
  int b = blockIdx.x;
  int lane = threadIdx.x & 63, wv = threadIdx.x >> 6;
  const float* src = oh + (size_t)b * DD;
#pragma unroll
  for (int k = 0; k < 4; k++)
    row[threadIdx.x + 256 * k] = src[threadIdx.x + 256 * k];
  __syncthreads();
  if (wv == 0) {
    float n2p = 0.f;
#pragma unroll
    for (int k = 0; k < 4; k++) {
      float4 v = ((const float4*)row)[lane + 64 * k];
      n2p += v.x * v.x + v.y * v.y + v.z * v.z + v.w * v.w;
    }
    n2p = wsum(n2p);
    if (lane == 0) s_n2 = n2p;
  }
#pragma unroll
  for (int ccc = 0; ccc < 4; ccc++) {
    int c = wv * 4 + ccc;
    const float4* pp4 = (const float4*)(p_p + (size_t)c * DD);
    const float4* ap4 = (const float4*)(a_p + (size_t)c * DD);
    float dp = 0.f, da = 0.f;
#pragma unroll
    for (int k = 0; k < 4; k++) {
      int d4 = lane + 64 * k;
      float4 v = ((const float4*)row)[d4];
      float4 p4 = pp4[d4];
      float4 a4 = ap4[d4];
      dp += p4.x * v.x + p4.y * v.y + p4.z * v.z + p4.w * v.w;
      da += a4.x * v.x + a4.y * v.y + a4.z * v.z + a4.w * v.w;
    }
    dp = wsum(dp); da = wsum(da);
    if (lane == 0) { dots[c][0] = dp; dots[c][1] = da; }
  }
  __syncthreads();
  if (threadIdx.x < CC) {
    int c = threadIdx.x;
    float n2 = s_n2;
    float n1 = sqrtf(n2);
    float rc = SCF * n1;
    float g = asinhf(rc) / fmaxf(rc, EPSF);
    float nu = fmaxf(n1 * g, 1e-15f);
    float fac = tanhf(SCF * nu) / (SCF * nu);
    float s = g * fac;
    float ny = fmaxf(n1 * s, 1e-15f);
    float maxn = (1.0f - 0.004f) / SCF;
    if (ny > maxn) s *= maxn / ny;
    float y2 = s * s * n2;
    float py = s * dots[c][0];
    float ay = s * dots[c][1];
    float x2 = cs[c * 5 + 0], conf = cs[c * 5 + 1], a_norm = cs[c * 5 + 2];
    float kk = cs[c * 5 + 3], xa = cs[c * 5 + 4];
    float xy = -py;
    float A = 1.f + 2.f * CURVF * xy + CURVF * y2;
    float den0 = 1.f + 2.f * CURVF * xy + CURVF * CURVF * x2 * y2;
    float d = den0 + 1e-5f;
    float num = 2.f * SCF * (A * xa + conf * ay) / d;
    float mob2 = (A * A * x2 + 2.f * A * conf * xy + conf * conf * y2) / (d * d);
    float denl = a_norm * (1.f - CURVF * mob2);
    logits[(size_t)b * CC + c] = kk * asinhf(num / denl);
  }
}

// ---------------------------------------------------------------------------
// Launcher
// ---------------------------------------------------------------------------
extern "C" void kernel_launch(void* const* d_in, const int* in_sizes, int n_in,
                              void* d_out, int out_size, void* d_ws, size_t ws_size,
                              hipStream_t stream) {
  const float* order_hyp  = (const float*)d_in[0];
  const float* family_hyp = (const float*)d_in[1];
  const float* order_euc  = (const float*)d_in[2];
  const float* family_euc = (const float*)d_in[3];
  const float* order      = (const float*)d_in[4];
  const float* family     = (const float*)d_in[5];
  const int*   mask       = (const int*)d_in[6];
  const float* in_proj_w  = (const float*)d_in[7];
  const float* in_proj_b  = (const float*)d_in[8];
  const float* out_proj_w = (const float*)d_in[9];
  const float* out_proj_b = (const float*)d_in[10];
  const float* ln_w       = (const float*)d_in[11];
  const float* ln_b       = (const float*)d_in[12];
  const float* to_w       = (const float*)d_in[13];
  const float* to_b       = (const float*)d_in[14];
  const float* tf_w       = (const float*)d_in[15];
  const float* tf_b       = (const float*)d_in[16];
  const float* mlr_a      = (const float*)d_in[17];
  const float* mlr_p      = (const float*)d_in[18];
  float* dout = (float*)d_out;

  char* w = (char*)d_ws;
  size_t off = 0;
  auto take = [&](size_t n) { char* p = w + off; off += (n + 255) & ~(size_t)255; return p; };
  unsigned short* gf_bf   = (unsigned short*)take((size_t)M1 * DD * 2);
  unsigned short* region2 = (unsigned short*)take((size_t)M1 * 3 * DD * 2);
  unsigned short* o_bf    = (unsigned short*)take((size_t)M1 * DD * 2);
  unsigned short* win_bf  = (unsigned short*)take((size_t)3 * DD * DD * 2);
  unsigned short* wout_bf = (unsigned short*)take((size_t)DD * DD * 2);
  unsigned short* tow_bf  = (unsigned short*)take((size_t)DD * TT * 2);
  unsigned short* tfw_bf  = (unsigned short*)take((size_t)DD * TT * 2);
  unsigned short* ord_bf  = (unsigned short*)take((size_t)BB * TT * 2);
  unsigned short* fam_bf  = (unsigned short*)take((size_t)BB * TT * 2);
  float* p_p   = (float*)take((size_t)CC * DD * 4);
  float* a_p   = (float*)take((size_t)CC * DD * 4);
  float* cs    = (float*)take(CC * 5 * 4);
  float* pens  = (float*)take((size_t)2 * BB * 4);

  unsigned short* qkv     = region2;
  unsigned short* attn_bf = region2;
  float* ofeat = (float*)((char*)region2 + 33554432);
  float* ffeat = (float*)((char*)region2 + 50331648);

  // merged bf16 converts
  Cvt6 cv;
  cv.src[0] = (const float4*)in_proj_w;  cv.dst[0] = win_bf;
  cv.src[1] = (const float4*)out_proj_w; cv.dst[1] = wout_bf;
  cv.src[2] = (const float4*)to_w;       cv.dst[2] = tow_bf;
  cv.src[3] = (const float4*)tf_w;       cv.dst[3] = tfw_bf;
  cv.src[4] = (const float4*)order;      cv.dst[4] = ord_bf;
  cv.src[5] = (const float4*)family;     cv.dst[5] = fam_bf;
  unsigned int n4[6] = {3u * DD * DD / 4, DD * DD / 4, DD * TT / 4, DD * TT / 4,
                        BB * TT / 4, BB * TT / 4};
  unsigned int acc4 = 0;
  for (int j = 0; j < 6; j++) { acc4 += n4[j]; cv.end4[j] = acc4; }
  k_cvt6<<<(acc4 + 255) / 256, 256, 0, stream>>>(cv, acc4);

  k_prep_gf<<<BB, 256, 0, stream>>>(order_hyp, family_hyp, order_euc, family_euc, gf_bf);

  // qkv = gf @ in_proj_w^T + b    (16384 x 3072, K=1024), 256² 8-phase GEMM
  {
    int nx = 3 * DD / 256, ny = M1 / 256;           // 12 x 64 = 768 wgs
    k_gemm256<1><<<nx * ny, 512, 0, stream>>>(
        gf_bf, win_bf, in_proj_b, qkv, 3 * DD, DD, nx);
  }

  k_attn<<<dim3(BB, HH), 256, 0, stream>>>(qkv, o_bf);

  // attn = o @ out_proj_w^T + b   (16384 x 1024, K=1024), 256² 8-phase GEMM
  {
    int nx = DD / 256, ny = M1 / 256;               // 4 x 64 = 256 wgs
    k_gemm256<1><<<nx * ny, 512, 0, stream>>>(
        o_bf, wout_bf, out_proj_b, attn_bf, DD, DD, nx);
  }

  k_ln_split<<<M1, 256, 0, stream>>>(gf_bf, attn_bf, ln_w, ln_b, dout);

  // both loss GEMMs: (4096 x 1024, K=768) x2 in one dispatch (128² path)
  k_gemm_loss<<<dim3(DD / 128, BB / 128, 2), 256, 0, stream>>>(
      ord_bf, tow_bf, to_b, ofeat, fam_bf, tfw_bf, tf_b, ffeat, BB, DD, TT);

  // cone penalties -> per-block partials (no atomics), then tiny reduce
  k_oxy<<<dim3(BB, 2), 256, 0, stream>>>(ofeat, dout + OFF_FH, ffeat, dout + OFF_OH, pens);
  k_finalize_loss<<<1, 256, 0, stream>>>(pens, mask, dout);

  k_mlr_prep<<<CC, 256, 0, stream>>>(mlr_a, mlr_p, p_p, a_p, cs);
  k_mlr_logits<<<BB, 256, 0, stream>>>(dout + OFF_OH, p_p, a_p, cs, dout + OFF_LOGITS);

  (void)in_sizes; (void)n_in; (void)out_size; (void)ws_size;
}

// Round 7
// 456.382 us; speedup vs baseline: 1.0318x; 1.0318x over previous
//
#include <hip/hip_runtime.h>
#include <stdint.h>

// ---------------------------------------------------------------------------
// Problem constants
// ---------------------------------------------------------------------------
#define BB    4096
#define DD    1024
#define TT    768
#define CC    16
#define HH    4
#define SS    4
#define HD    256
#define M1    (BB*SS)     // 16384 rows
#define CURVF 0.05f
#define SCF   0.22360679774997896f   // sqrt(0.05)
#define EPSF  1e-8f
#define ASINH_MAXF 11.090354888959125f  // asinh(2^15)

// d_out element offsets: [logits B*C][loss 1][oh B*D][fh B*D][oeu B*D][feu B*D]
#define OFF_LOGITS 0ull
#define OFF_LOSS   65536ull
#define OFF_OH     65537ull
#define OFF_FH     (65537ull + 4194304ull)
#define OFF_OEU    (65537ull + 2ull*4194304ull)
#define OFF_FEU    (65537ull + 3ull*4194304ull)

typedef __attribute__((ext_vector_type(8))) short bf16x8;
typedef __attribute__((ext_vector_type(4))) float f32x4;

__device__ __forceinline__ float bf2f(unsigned short h) {
  union { unsigned int u; float f; } v; v.u = ((unsigned int)h) << 16; return v.f;
}
__device__ __forceinline__ unsigned short f2bf(float f) {
  union { float f; unsigned int u; } v; v.f = f;
  unsigned int u = v.u;
  return (unsigned short)((u + 0x7FFFu + ((u >> 16) & 1u)) >> 16);
}
__device__ __forceinline__ ushort4 f2bf4(float4 v) {
  ushort4 o; o.x = f2bf(v.x); o.y = f2bf(v.y); o.z = f2bf(v.z); o.w = f2bf(v.w);
  return o;
}
__device__ __forceinline__ float wsum(float v) {
#pragma unroll
  for (int o = 32; o > 0; o >>= 1) v += __shfl_xor(v, o, 64);
  return v;
}
__device__ __forceinline__ float block_sum(float v, float* red) {
  v = wsum(v);
  int lane = threadIdx.x & 63, wv = threadIdx.x >> 6;
  __syncthreads();
  if (lane == 0) red[wv] = v;
  __syncthreads();
  return red[0] + red[1] + red[2] + red[3];
}
__device__ __forceinline__ float artanh_clip(float x) {
  x = fminf(fmaxf(x, -1.0f + 1e-5f), 1.0f - 1e-5f);
  return 0.5f * (log1pf(x) - log1pf(-x));
}

typedef __attribute__((address_space(1))) const void gas_void;
typedef __attribute__((address_space(3))) void las_void;
__device__ __forceinline__ void gld16(void* l, const void* g) {
  __builtin_amdgcn_global_load_lds((gas_void*)g, (las_void*)l, 16, 0, 0);
}

#define VMCNT(n) asm volatile("s_waitcnt vmcnt(" #n ")" ::: "memory")

// ---------------------------------------------------------------------------
// k_front: fused {p_logmap0 gf-prep} ∪ {mlr precompute} ∪ {fp32->bf16 convert}
// All three are input-only producers with no mutual deps; fusing cuts 2
// kernel launches from the serial stream.
// Grid: [0, BB)           -> prep_gf row b
//       [BB, BB+CC)       -> mlr_prep class c
//       [BB+CC, ...)      -> cvt6 chunk
// ---------------------------------------------------------------------------
struct Cvt6 {
  const float4* src[6];
  unsigned short* dst[6];
  unsigned int end4[6];   // cumulative float4 counts
};

__device__ __forceinline__ void prep_gf_body(const float* __restrict__ ohyp,
    const float* __restrict__ fhyp, const float* __restrict__ oeuc,
    const float* __restrict__ feuc, unsigned short* __restrict__ gf,
    int b, float* red) {
  int t = threadIdx.x;
  size_t base4 = (size_t)b * (DD / 4);
  float4 xo = ((const float4*)ohyp)[base4 + t];
  float4 xf = ((const float4*)fhyp)[base4 + t];
  float so = xo.x * xo.x + xo.y * xo.y + xo.z * xo.z + xo.w * xo.w;
  float sf = xf.x * xf.x + xf.y * xf.y + xf.z * xf.z + xf.w * xf.w;
  float no2 = block_sum(so, red);
  float nf2 = block_sum(sf, red);
  float no = fmaxf(sqrtf(no2), 1e-15f);
  float nf = fmaxf(sqrtf(nf2), 1e-15f);
  float fo = artanh_clip(SCF * no) / (no * SCF);
  float ff = artanh_clip(SCF * nf) / (nf * SCF);
  size_t g0 = (size_t)b * 4 * (DD / 4);
  float4 e2 = ((const float4*)oeuc)[base4 + t];
  float4 e3 = ((const float4*)feuc)[base4 + t];
  float4 y0 = {xo.x * fo, xo.y * fo, xo.z * fo, xo.w * fo};
  float4 y1 = {xf.x * ff, xf.y * ff, xf.z * ff, xf.w * ff};
  ((ushort4*)gf)[g0 + t]              = f2bf4(y0);
  ((ushort4*)gf)[g0 + DD / 4 + t]     = f2bf4(y1);
  ((ushort4*)gf)[g0 + 2 * DD / 4 + t] = f2bf4(e2);
  ((ushort4*)gf)[g0 + 3 * DD / 4 + t] = f2bf4(e3);
}

__device__ __forceinline__ void mlr_prep_body(const float* __restrict__ a,
    const float* __restrict__ p, float* __restrict__ p_p, float* __restrict__ a_p,
    float* __restrict__ cs, int c, float* red) {
  int t = threadIdx.x;
  size_t base4 = (size_t)c * (DD / 4);
  float4 pv = ((const float4*)p)[base4 + t];
  float4 av = ((const float4*)a)[base4 + t];
  float sp = pv.x * pv.x + pv.y * pv.y + pv.z * pv.z + pv.w * pv.w;
  float sa = av.x * av.x + av.y * av.y + av.z * av.z + av.w * av.w;
  float spa = pv.x * av.x + pv.y * av.y + pv.z * av.z + pv.w * av.w;
  sp = block_sum(sp, red); sa = block_sum(sa, red); spa = block_sum(spa, red);
  float n = fmaxf(sqrtf(sp), 1e-15f);
  float f = tanhf(SCF * n) / (SCF * n);
  float x2 = f * f * sp;
  float conf = 1.0f - CURVF * x2;
  float a_norm = fabsf(conf) * sqrtf(sa);
  float lam = 2.0f / (1.0f - CURVF * x2);
  float kk = lam * a_norm / SCF;
  float xa = -f * conf * spa;
  float4 pp = {pv.x * f, pv.y * f, pv.z * f, pv.w * f};
  float4 ap = {av.x * conf, av.y * conf, av.z * conf, av.w * conf};
  ((float4*)p_p)[base4 + t] = pp;
  ((float4*)a_p)[base4 + t] = ap;
  if (threadIdx.x == 0) {
    cs[c * 5 + 0] = x2; cs[c * 5 + 1] = conf; cs[c * 5 + 2] = a_norm;
    cs[c * 5 + 3] = kk; cs[c * 5 + 4] = xa;
  }
}

__global__ __launch_bounds__(256) void k_front(
    const float* __restrict__ ohyp, const float* __restrict__ fhyp,
    const float* __restrict__ oeuc, const float* __restrict__ feuc,
    unsigned short* __restrict__ gf,
    const float* __restrict__ mlr_a, const float* __restrict__ mlr_p,
    float* __restrict__ p_p, float* __restrict__ a_p, float* __restrict__ cs,
    Cvt6 cv, unsigned int total4) {
  __shared__ float red[4];
  unsigned int blk = blockIdx.x;
  if (blk < BB) {
    prep_gf_body(ohyp, fhyp, oeuc, feuc, gf, (int)blk, red);
    return;
  }
  if (blk < BB + CC) {
    mlr_prep_body(mlr_a, mlr_p, p_p, a_p, cs, (int)(blk - BB), red);
    return;
  }
  unsigned int i = (blk - BB - CC) * 256 + threadIdx.x;
  if (i >= total4) return;
#pragma unroll
  for (int j = 0; j < 6; j++) {
    if (i < cv.end4[j]) {
      unsigned int k = i - (j ? cv.end4[j - 1] : 0u);
      ((ushort4*)cv.dst[j])[k] = f2bf4(cv.src[j][k]);
      return;
    }
  }
}

// ---------------------------------------------------------------------------
// 256x256-tile bf16 GEMM, C = A(MxK) * Bm(NxK)^T + bias.  [R3-verified best:
// 118 us QKV, 874 TF, 0 bank conflicts]
// 8 waves (2Mx4N), BK=32, 4-deep LDS ring (4 x 32KB = 128KB), counted
// vmcnt(8) pipeline, setprio around MFMA clusters, XCD swizzle.
// XOR involution swizzle: stage from pre-swizzled global column
// lc = (tid&3) ^ ((srow>>1)&3) into LINEAR LDS dest (global_load_lds rule),
// read back at chunk (hi ^ ((fr>>1)&3)). Lanes 0-7 hit 8 distinct bank-quads.
// NOTE (R4/R5 post-mortem): the finer 8-phase schedule with per-phase
// lgkmcnt(0)+sched_barrier(0) fences REGRESSED to 832 TF — the fences block
// compiler VALU/MFMA interleave. Both structures sit at the ~900 TF
// m97-structure ceiling; this one is the measured best.
// ---------------------------------------------------------------------------
template <int OUT_BF16>
__global__ __launch_bounds__(512) void k_gemm256(
    const unsigned short* __restrict__ A, const unsigned short* __restrict__ Bm,
    const float* __restrict__ bias, void* __restrict__ Cv,
    int N, int K, int nx) {
  __shared__ unsigned short lds[4][2][8192];   // [buf][A/B][256*32]
  const int nwg = gridDim.x;
  const int rid = blockIdx.x;
  const int wg = (rid & 7) * (nwg >> 3) + (rid >> 3);  // XCD-contiguous (nwg%8==0)
  const int bx = wg % nx;
  const int by = wg / nx;
  const long tileM = (long)by * 256;
  const long tileN = (long)bx * 256;
  const int tid = threadIdx.x;
  const int lane = tid & 63;
  const int wv = tid >> 6;       // 0..7
  const int wr = wv >> 2;        // 0..1  (M half)
  const int wc = wv & 3;         // 0..3  (N quarter)
  const int NT = K >> 5;         // K-tiles of 32

  f32x4 acc[8][4];
#pragma unroll
  for (int i = 0; i < 8; i++)
#pragma unroll
    for (int j = 0; j < 4; j++) acc[i][j] = (f32x4){0.f, 0.f, 0.f, 0.f};

  const int srow = tid >> 2;                 // 0..127
  const int lc = (tid & 3) ^ ((srow >> 1) & 3);
  const unsigned short* Ag = A + (tileM + srow) * (long)K + lc * 8;
  const unsigned short* Bg = Bm + (tileN + srow) * (long)K + lc * 8;

  auto stageA = [&](int t) {
    int b = t & 3;
    const unsigned short* s = Ag + t * 32;
    gld16(&lds[b][0][tid * 8], s);
    gld16(&lds[b][0][4096 + tid * 8], s + (long)128 * K);
  };
  auto stageB = [&](int t) {
    int b = t & 3;
    const unsigned short* s = Bg + t * 32;
    gld16(&lds[b][1][tid * 8], s);
    gld16(&lds[b][1][4096 + tid * 8], s + (long)128 * K);
  };

  // prologue: 3 K-tiles in flight; wait only for tile 0 (newest 8 = tiles 1,2)
  stageA(0); stageB(0);
  stageA(1); stageB(1);
  stageA(2); stageB(2);
  VMCNT(8);
  __builtin_amdgcn_s_barrier();
  asm volatile("" ::: "memory");

  const int fr = lane & 15;
  const int hi = lane >> 4;
  const int fko = (hi ^ ((fr >> 1) & 3)) * 8;   // swizzled read chunk

  for (int t = 0; t < NT; ++t) {
    const unsigned short* Ab = &lds[t & 3][0][0];
    const unsigned short* Bb = &lds[t & 3][1][0];
    bf16x8 af[4], bfr[4];
    // ---- phase 1: B frags + A frags 0-3, stage A(t+3), 16 MFMA
#pragma unroll
    for (int j = 0; j < 4; j++)
      bfr[j] = *(const bf16x8*)(Bb + (wc * 64 + j * 16 + fr) * 32 + fko);
#pragma unroll
    for (int i = 0; i < 4; i++)
      af[i] = *(const bf16x8*)(Ab + (wr * 128 + i * 16 + fr) * 32 + fko);
    if (t + 3 < NT) stageA(t + 3);
    __builtin_amdgcn_s_setprio(1);
#pragma unroll
    for (int i = 0; i < 4; i++)
#pragma unroll
      for (int j = 0; j < 4; j++)
        acc[i][j] = __builtin_amdgcn_mfma_f32_16x16x32_bf16(af[i], bfr[j], acc[i][j], 0, 0, 0);
    __builtin_amdgcn_s_setprio(0);
    // ---- phase 2: A frags 4-7 (reuse B frags), stage B(t+3), 16 MFMA
#pragma unroll
    for (int i = 0; i < 4; i++)
      af[i] = *(const bf16x8*)(Ab + (wr * 128 + (i + 4) * 16 + fr) * 32 + fko);
    if (t + 3 < NT) stageB(t + 3);
    __builtin_amdgcn_s_setprio(1);
#pragma unroll
    for (int i = 0; i < 4; i++)
#pragma unroll
      for (int j = 0; j < 4; j++)
        acc[i + 4][j] = __builtin_amdgcn_mfma_f32_16x16x32_bf16(af[i], bfr[j], acc[i + 4][j], 0, 0, 0);
    __builtin_amdgcn_s_setprio(0);
    // ---- boundary: ensure tile t+1 landed. FIFO vmcnt: newest 8 loads are
    // tiles t+2,t+3 in steady state -> vmcnt(8); tighter at the tail.
    if (t + 1 < NT) {
      if (t + 3 < NT)      VMCNT(8);
      else if (t + 2 < NT) VMCNT(4);
      else                 VMCNT(0);
      __builtin_amdgcn_s_barrier();
      asm volatile("" ::: "memory");
    }
  }

  // epilogue
  const int er = hi * 4;
#pragma unroll
  for (int i = 0; i < 8; i++) {
#pragma unroll
    for (int j = 0; j < 4; j++) {
      long col = tileN + wc * 64 + j * 16 + fr;
      float bv = bias ? bias[col] : 0.f;
#pragma unroll
      for (int r = 0; r < 4; r++) {
        long row = tileM + wr * 128 + i * 16 + er + r;
        float v = acc[i][j][r] + bv;
        if (OUT_BF16) ((unsigned short*)Cv)[row * (long)N + col] = f2bf(v);
        else          ((float*)Cv)[row * (long)N + col] = v;
      }
    }
  }
}

// ---------------------------------------------------------------------------
// bf16 GEMM body (128x128 tile, 4 waves) — kept for the small loss GEMMs
// where a 256² grid would underfill the GPU (128 blocks).
// ---------------------------------------------------------------------------
template <int OUT_BF16>
__device__ __forceinline__ void gemm_body(
    unsigned short* As, unsigned short* Bs,
    const unsigned short* __restrict__ A, const unsigned short* __restrict__ Bm,
    const float* __restrict__ bias, void* __restrict__ Cv,
    int M, int N, int K, int bx, int by) {
  const int tid = threadIdx.x;
  const int lane = tid & 63;
  const int wv = tid >> 6;
  const long tileM = (long)by * 128;
  const long tileN = (long)bx * 128;

  f32x4 acc[4][4];
#pragma unroll
  for (int i = 0; i < 4; i++)
#pragma unroll
    for (int j = 0; j < 4; j++) acc[i][j] = (f32x4){0.f, 0.f, 0.f, 0.f};

  const int srow = wv * 16 + (lane >> 2);
  const int lc = (lane & 3) ^ ((srow >> 1) & 3);
  const unsigned short* Ag = A + (tileM + srow) * (long)K + lc * 8;
  const unsigned short* Bg = Bm + (tileN + srow) * (long)K + lc * 8;
  unsigned short* Asl = As + srow * 32 + (lane & 3) * 8;
  unsigned short* Bsl = Bs + srow * 32 + (lane & 3) * 8;

  const int fr = lane & 15;
  const int rkey = (fr >> 1) & 3;
  const int fko2 = (((lane >> 4) ^ rkey)) * 8;
  const int wr = (wv >> 1) * 64;
  const int wc = (wv & 1) * 64;

  for (int k0 = 0; k0 < K; k0 += 32) {
    gld16(Asl, Ag + k0);
    gld16(Asl + 64 * 32, Ag + (long)64 * K + k0);
    gld16(Bsl, Bg + k0);
    gld16(Bsl + 64 * 32, Bg + (long)64 * K + k0);
    __syncthreads();
    bf16x8 af[4], bfr[4];
#pragma unroll
    for (int i = 0; i < 4; i++)
      af[i] = *(const bf16x8*)(As + (wr + i * 16 + fr) * 32 + fko2);
#pragma unroll
    for (int j = 0; j < 4; j++)
      bfr[j] = *(const bf16x8*)(Bs + (wc + j * 16 + fr) * 32 + fko2);
#pragma unroll
    for (int i = 0; i < 4; i++)
#pragma unroll
      for (int j = 0; j < 4; j++)
        acc[i][j] = __builtin_amdgcn_mfma_f32_16x16x32_bf16(af[i], bfr[j], acc[i][j], 0, 0, 0);
    __syncthreads();
  }

  const int er = (lane >> 4) * 4;
  const int ec = lane & 15;
#pragma unroll
  for (int i = 0; i < 4; i++) {
#pragma unroll
    for (int j = 0; j < 4; j++) {
      long col = tileN + wc + j * 16 + ec;
      float bv = bias ? bias[col] : 0.f;
#pragma unroll
      for (int r = 0; r < 4; r++) {
        long row = tileM + wr + i * 16 + er + r;
        float v = acc[i][j][r] + bv;
        if (OUT_BF16) ((unsigned short*)Cv)[row * (long)N + col] = f2bf(v);
        else          ((float*)Cv)[row * (long)N + col] = v;
      }
    }
  }
}

__global__ __launch_bounds__(256) void k_gemm_loss(
    const unsigned short* __restrict__ A0, const unsigned short* __restrict__ B0,
    const float* __restrict__ b0, float* __restrict__ C0,
    const unsigned short* __restrict__ A1, const unsigned short* __restrict__ B1,
    const float* __restrict__ b1, float* __restrict__ C1, int M, int N, int K) {
  __shared__ unsigned short As[128 * 32];
  __shared__ unsigned short Bs[128 * 32];
  if (blockIdx.z == 0)
    gemm_body<0>(As, Bs, A0, B0, b0, C0, M, N, K, blockIdx.x, blockIdx.y);
  else
    gemm_body<0>(As, Bs, A1, B1, b1, C1, M, N, K, blockIdx.x, blockIdx.y);
}

// ---------------------------------------------------------------------------
// tiny attention: S=4, one block per (b,h); wave qi handles query qi.
// ---------------------------------------------------------------------------
__global__ __launch_bounds__(256) void k_attn(const unsigned short* __restrict__ qkv,
                                              unsigned short* __restrict__ o) {
  int b = blockIdx.x;
  int h = blockIdx.y;
  int lane = threadIdx.x & 63;
  int qi = threadIdx.x >> 6;
  const unsigned short* base = qkv + (size_t)b * 4 * 3072 + h * HD;
  int d = lane * 4;
  float qv[4], kv[4][4], vv[4][4];
  {
    ushort4 q4 = *(const ushort4*)(base + (size_t)qi * 3072 + d);
    qv[0] = bf2f(q4.x); qv[1] = bf2f(q4.y); qv[2] = bf2f(q4.z); qv[3] = bf2f(q4.w);
  }
#pragma unroll
  for (int j = 0; j < 4; j++) {
    ushort4 k4 = *(const ushort4*)(base + (size_t)j * 3072 + 1024 + d);
    ushort4 v4 = *(const ushort4*)(base + (size_t)j * 3072 + 2048 + d);
    kv[j][0] = bf2f(k4.x); kv[j][1] = bf2f(k4.y); kv[j][2] = bf2f(k4.z); kv[j][3] = bf2f(k4.w);
    vv[j][0] = bf2f(v4.x); vv[j][1] = bf2f(v4.y); vv[j][2] = bf2f(v4.z); vv[j][3] = bf2f(v4.w);
  }
  float sc_[4];
#pragma unroll
  for (int j = 0; j < 4; j++) {
    float p = 0.f;
#pragma unroll
    for (int t = 0; t < 4; t++) p += qv[t] * kv[j][t];
    sc_[j] = wsum(p) * (1.0f / 16.0f);
  }
  float mx = fmaxf(fmaxf(sc_[0], sc_[1]), fmaxf(sc_[2], sc_[3]));
  float e[4], den = 0.f;
#pragma unroll
  for (int j = 0; j < 4; j++) { e[j] = expf(sc_[j] - mx); den += e[j]; }
  float inv = 1.0f / den;
  float4 ov = {0.f, 0.f, 0.f, 0.f};
#pragma unroll
  for (int j = 0; j < 4; j++) {
    float w = e[j] * inv;
    ov.x += w * vv[j][0]; ov.y += w * vv[j][1];
    ov.z += w * vv[j][2]; ov.w += w * vv[j][3];
  }
  *(ushort4*)(o + (size_t)(b * 4 + qi) * DD + h * HD + d) = f2bf4(ov);
}

// ---------------------------------------------------------------------------
// layernorm(gf + attn) then split; s<2 additionally l_expmap0.
// ---------------------------------------------------------------------------
__global__ __launch_bounds__(256) void k_ln_split(const unsigned short* __restrict__ gf,
    const unsigned short* __restrict__ attn, const float* __restrict__ lnw,
    const float* __restrict__ lnb, float* __restrict__ dout) {
  __shared__ float red[4];
  int r = blockIdx.x;
  int b = r >> 2, s = r & 3;
  int t = threadIdx.x;
  size_t base4 = (size_t)r * (DD / 4);
  ushort4 g4 = ((const ushort4*)gf)[base4 + t];
  ushort4 a4 = ((const ushort4*)attn)[base4 + t];
  float x[4] = {bf2f(g4.x) + bf2f(a4.x), bf2f(g4.y) + bf2f(a4.y),
                bf2f(g4.z) + bf2f(a4.z), bf2f(g4.w) + bf2f(a4.w)};
  float sum = x[0] + x[1] + x[2] + x[3];
  float sq = x[0] * x[0] + x[1] * x[1] + x[2] * x[2] + x[3] * x[3];
  sum = block_sum(sum, red);
  sq  = block_sum(sq, red);
  float mu = sum * (1.0f / (float)DD);
  float var = sq * (1.0f / (float)DD) - mu * mu;
  float inv = rsqrtf(var + 1e-5f);
  float4 w4 = ((const float4*)lnw)[t];
  float4 b4 = ((const float4*)lnb)[t];
  float y[4];
  y[0] = (x[0] - mu) * inv * w4.x + b4.x;
  y[1] = (x[1] - mu) * inv * w4.y + b4.y;
  y[2] = (x[2] - mu) * inv * w4.z + b4.z;
  y[3] = (x[3] - mu) * inv * w4.w + b4.w;
  float fmul = 1.0f;
  if (s < 2) {
    float n2 = y[0] * y[0] + y[1] * y[1] + y[2] * y[2] + y[3] * y[3];
    n2 = block_sum(n2, red);
    float rc = SCF * sqrtf(n2);
    float si = fminf(fmaxf(rc, EPSF), ASINH_MAXF);
    fmul = sinhf(si) / fmaxf(rc, EPSF);
  }
  size_t offs = (s == 0) ? OFF_OH : (s == 1) ? OFF_FH : (s == 2) ? OFF_OEU : OFF_FEU;
  float4* outp = (float4*)(dout + offs + (size_t)b * DD);
  float4 o4 = {y[0] * fmul, y[1] * fmul, y[2] * fmul, y[3] * fmul};
  outp[t] = o4;
}

// ---------------------------------------------------------------------------
// cone loss: per row b, pen -> pens[which*BB + b]. NO atomics.
// ---------------------------------------------------------------------------
__global__ __launch_bounds__(256) void k_oxy(const float* __restrict__ raw0,
    const float* __restrict__ y0, const float* __restrict__ raw1,
    const float* __restrict__ y1, float* __restrict__ pens) {
  __shared__ float red[4];
  int b = blockIdx.x;
  int which = blockIdx.y;
  const float* raw = which ? raw1 : raw0;
  const float* yr  = which ? y1 : y0;
  size_t base = (size_t)b * DD;
  float sxx = 0.f, sxy = 0.f, syy = 0.f;
#pragma unroll
  for (int k = 0; k < 4; k++) {
    int d = threadIdx.x + 256 * k;
    float xv = raw[base + d];
    float yv = yr[base + d];
    sxx += xv * xv; sxy += xv * yv; syy += yv * yv;
  }
  sxx = block_sum(sxx, red);
  sxy = block_sum(sxy, red);
  syy = block_sum(syy, red);
  if (threadIdx.x == 0) {
    float nraw = sqrtf(sxx);
    float rc = SCF * nraw;
    float si = fminf(fmaxf(rc, EPSF), ASINH_MAXF);
    float f = sinhf(si) / fmaxf(rc, EPSF);
    float x2 = f * f * sxx;
    float xy = f * sxy;
    float y2 = syy;
    float nx = f * nraw;
    float xt = sqrtf(1.0f / CURVF + x2);
    float yt = sqrtf(1.0f / CURVF + y2);
    float c_xyl = CURVF * (xy - xt * yt);
    float num = yt + c_xyl * xt;
    float den = sqrtf(fmaxf(c_xyl * c_xyl - 1.0f, EPSF));
    float ai = num / (nx * den + EPSF);
    ai = fminf(fmaxf(ai, -1.0f + EPSF), 1.0f - EPSF);
    float ang = acosf(ai);
    float asi = 0.2f / (nx * SCF + EPSF);
    asi = fminf(fmaxf(asi, -1.0f + EPSF), 1.0f - EPSF);
    float ap = asinf(asi);
    pens[(size_t)which * BB + b] = fmaxf(ang - ap, 0.0f);
  }
}

// ---------------------------------------------------------------------------
// k_back: fused {MLR logits} ∪ {loss finalize}.
// Grid: [0, BB) -> mlr_logits row b;  BB -> finalize_loss.
// ---------------------------------------------------------------------------
__global__ __launch_bounds__(256) void k_back(const float* __restrict__ oh,
    const float* __restrict__ p_p, const float* __restrict__ a_p,
    const float* __restrict__ cs, float* __restrict__ logits,
    const float* __restrict__ pens, const int* __restrict__ mask,
    float* __restrict__ dout) {
  __shared__ float row[DD];
  __shared__ float dots[CC][2];
  __shared__ float s_n2;
  __shared__ float red[4];
  int blk = blockIdx.x;
  int lane = threadIdx.x & 63, wv = threadIdx.x >> 6;

  if (blk == BB) {
    // ---- finalize_loss
    float s0 = 0.f, s1 = 0.f, cnt = 0.f;
    for (int i = threadIdx.x; i < BB; i += 256) {
      s0 += pens[i];
      float m = (float)mask[i];
      s1 += pens[BB + i] * m;
      cnt += m;
    }
    s0 = block_sum(s0, red);
    s1 = block_sum(s1, red);
    cnt = block_sum(cnt, red);
    if (threadIdx.x == 0) {
      float order_loss = s0 / (float)BB;
      float fam = (cnt > 0.f) ? s1 / fmaxf(cnt, 1.0f) : 0.0f;
      dout[OFF_LOSS] = order_loss + fam;
    }
    return;
  }

  // ---- mlr_logits
  int b = blk;
  const float* src = oh + (size_t)b * DD;
#pragma unroll
  for (int k = 0; k < 4; k++)
    row[threadIdx.x + 256 * k] = src[threadIdx.x + 256 * k];
  __syncthreads();
  if (wv == 0) {
    float n2p = 0.f;
#pragma unroll
    for (int k = 0; k < 4; k++) {
      float4 v = ((const float4*)row)[lane + 64 * k];
      n2p += v.x * v.x + v.y * v.y + v.z * v.z + v.w * v.w;
    }
    n2p = wsum(n2p);
    if (lane == 0) s_n2 = n2p;
  }
#pragma unroll
  for (int ccc = 0; ccc < 4; ccc++) {
    int c = wv * 4 + ccc;
    const float4* pp4 = (const float4*)(p_p + (size_t)c * DD);
    const float4* ap4 = (const float4*)(a_p + (size_t)c * DD);
    float dp = 0.f, da = 0.f;
#pragma unroll
    for (int k = 0; k < 4; k++) {
      int d4 = lane + 64 * k;
      float4 v = ((const float4*)row)[d4];
      float4 p4 = pp4[d4];
      float4 a4 = ap4[d4];
      dp += p4.x * v.x + p4.y * v.y + p4.z * v.z + p4.w * v.w;
      da += a4.x * v.x + a4.y * v.y + a4.z * v.z + a4.w * v.w;
    }
    dp = wsum(dp); da = wsum(da);
    if (lane == 0) { dots[c][0] = dp; dots[c][1] = da; }
  }
  __syncthreads();
  if (threadIdx.x < CC) {
    int c = threadIdx.x;
    float n2 = s_n2;
    float n1 = sqrtf(n2);
    float rc = SCF * n1;
    float g = asinhf(rc) / fmaxf(rc, EPSF);
    float nu = fmaxf(n1 * g, 1e-15f);
    float fac = tanhf(SCF * nu) / (SCF * nu);
    float s = g * fac;
    float ny = fmaxf(n1 * s, 1e-15f);
    float maxn = (1.0f - 0.004f) / SCF;
    if (ny > maxn) s *= maxn / ny;
    float y2 = s * s * n2;
    float py = s * dots[c][0];
    float ay = s * dots[c][1];
    float x2 = cs[c * 5 + 0], conf = cs[c * 5 + 1], a_norm = cs[c * 5 + 2];
    float kk = cs[c * 5 + 3], xa = cs[c * 5 + 4];
    float xy = -py;
    float A = 1.f + 2.f * CURVF * xy + CURVF * y2;
    float den0 = 1.f + 2.f * CURVF * xy + CURVF * CURVF * x2 * y2;
    float d = den0 + 1e-5f;
    float num = 2.f * SCF * (A * xa + conf * ay) / d;
    float mob2 = (A * A * x2 + 2.f * A * conf * xy + conf * conf * y2) / (d * d);
    float denl = a_norm * (1.f - CURVF * mob2);
    logits[(size_t)b * CC + c] = kk * asinhf(num / denl);
  }
}

// ---------------------------------------------------------------------------
// Launcher
// ---------------------------------------------------------------------------
extern "C" void kernel_launch(void* const* d_in, const int* in_sizes, int n_in,
                              void* d_out, int out_size, void* d_ws, size_t ws_size,
                              hipStream_t stream) {
  const float* order_hyp  = (const float*)d_in[0];
  const float* family_hyp = (const float*)d_in[1];
  const float* order_euc  = (const float*)d_in[2];
  const float* family_euc = (const float*)d_in[3];
  const float* order      = (const float*)d_in[4];
  const float* family     = (const float*)d_in[5];
  const int*   mask       = (const int*)d_in[6];
  const float* in_proj_w  = (const float*)d_in[7];
  const float* in_proj_b  = (const float*)d_in[8];
  const float* out_proj_w = (const float*)d_in[9];
  const float* out_proj_b = (const float*)d_in[10];
  const float* ln_w       = (const float*)d_in[11];
  const float* ln_b       = (const float*)d_in[12];
  const float* to_w       = (const float*)d_in[13];
  const float* to_b       = (const float*)d_in[14];
  const float* tf_w       = (const float*)d_in[15];
  const float* tf_b       = (const float*)d_in[16];
  const float* mlr_a      = (const float*)d_in[17];
  const float* mlr_p      = (const float*)d_in[18];
  float* dout = (float*)d_out;

  char* w = (char*)d_ws;
  size_t off = 0;
  auto take = [&](size_t n) { char* p = w + off; off += (n + 255) & ~(size_t)255; return p; };
  unsigned short* gf_bf   = (unsigned short*)take((size_t)M1 * DD * 2);
  unsigned short* region2 = (unsigned short*)take((size_t)M1 * 3 * DD * 2);
  unsigned short* o_bf    = (unsigned short*)take((size_t)M1 * DD * 2);
  unsigned short* win_bf  = (unsigned short*)take((size_t)3 * DD * DD * 2);
  unsigned short* wout_bf = (unsigned short*)take((size_t)DD * DD * 2);
  unsigned short* tow_bf  = (unsigned short*)take((size_t)DD * TT * 2);
  unsigned short* tfw_bf  = (unsigned short*)take((size_t)DD * TT * 2);
  unsigned short* ord_bf  = (unsigned short*)take((size_t)BB * TT * 2);
  unsigned short* fam_bf  = (unsigned short*)take((size_t)BB * TT * 2);
  float* p_p   = (float*)take((size_t)CC * DD * 4);
  float* a_p   = (float*)take((size_t)CC * DD * 4);
  float* cs    = (float*)take(CC * 5 * 4);
  float* pens  = (float*)take((size_t)2 * BB * 4);

  unsigned short* qkv     = region2;
  unsigned short* attn_bf = region2;
  float* ofeat = (float*)((char*)region2 + 33554432);
  float* ffeat = (float*)((char*)region2 + 50331648);

  // ---- fused front: prep_gf + mlr_prep + bf16 converts
  Cvt6 cv;
  cv.src[0] = (const float4*)in_proj_w;  cv.dst[0] = win_bf;
  cv.src[1] = (const float4*)out_proj_w; cv.dst[1] = wout_bf;
  cv.src[2] = (const float4*)to_w;       cv.dst[2] = tow_bf;
  cv.src[3] = (const float4*)tf_w;       cv.dst[3] = tfw_bf;
  cv.src[4] = (const float4*)order;      cv.dst[4] = ord_bf;
  cv.src[5] = (const float4*)family;     cv.dst[5] = fam_bf;
  unsigned int n4[6] = {3u * DD * DD / 4, DD * DD / 4, DD * TT / 4, DD * TT / 4,
                        BB * TT / 4, BB * TT / 4};
  unsigned int acc4 = 0;
  for (int j = 0; j < 6; j++) { acc4 += n4[j]; cv.end4[j] = acc4; }
  unsigned int cvtBlocks = (acc4 + 255) / 256;
  k_front<<<BB + CC + cvtBlocks, 256, 0, stream>>>(
      order_hyp, family_hyp, order_euc, family_euc, gf_bf,
      mlr_a, mlr_p, p_p, a_p, cs, cv, acc4);

  // qkv = gf @ in_proj_w^T + b    (16384 x 3072, K=1024), 256² pipelined GEMM
  {
    int nx = 3 * DD / 256, ny = M1 / 256;           // 12 x 64 = 768 wgs
    k_gemm256<1><<<nx * ny, 512, 0, stream>>>(
        gf_bf, win_bf, in_proj_b, qkv, 3 * DD, DD, nx);
  }

  k_attn<<<dim3(BB, HH), 256, 0, stream>>>(qkv, o_bf);

  // attn = o @ out_proj_w^T + b   (16384 x 1024, K=1024), 256² pipelined GEMM
  {
    int nx = DD / 256, ny = M1 / 256;               // 4 x 64 = 256 wgs
    k_gemm256<1><<<nx * ny, 512, 0, stream>>>(
        o_bf, wout_bf, out_proj_b, attn_bf, DD, DD, nx);
  }

  k_ln_split<<<M1, 256, 0, stream>>>(gf_bf, attn_bf, ln_w, ln_b, dout);

  // both loss GEMMs: (4096 x 1024, K=768) x2 in one dispatch (128² path)
  k_gemm_loss<<<dim3(DD / 128, BB / 128, 2), 256, 0, stream>>>(
      ord_bf, tow_bf, to_b, ofeat, fam_bf, tfw_bf, tf_b, ffeat, BB, DD, TT);

  // cone penalties -> per-block partials (no atomics)
  k_oxy<<<dim3(BB, 2), 256, 0, stream>>>(ofeat, dout + OFF_FH, ffeat, dout + OFF_OH, pens);

  // ---- fused back: mlr_logits + finalize_loss
  k_back<<<BB + 1, 256, 0, stream>>>(dout + OFF_OH, p_p, a_p, cs,
                                     dout + OFF_LOGITS, pens, mask, dout);

  (void)in_sizes; (void)n_in; (void)out_size; (void)ws_size;
}

// Round 8
// 445.065 us; speedup vs baseline: 1.0580x; 1.0254x over previous
//
#include <hip/hip_runtime.h>
#include <stdint.h>

// ---------------------------------------------------------------------------
// Problem constants
// ---------------------------------------------------------------------------
#define BB    4096
#define DD    1024
#define TT    768
#define CC    16
#define HH    4
#define SS    4
#define HD    256
#define M1    (BB*SS)     // 16384 rows
#define CURVF 0.05f
#define SCF   0.22360679774997896f   // sqrt(0.05)
#define EPSF  1e-8f
#define ASINH_MAXF 11.090354888959125f  // asinh(2^15)

// d_out element offsets: [logits B*C][loss 1][oh B*D][fh B*D][oeu B*D][feu B*D]
#define OFF_LOGITS 0ull
#define OFF_LOSS   65536ull
#define OFF_OH     65537ull
#define OFF_FH     (65537ull + 4194304ull)
#define OFF_OEU    (65537ull + 2ull*4194304ull)
#define OFF_FEU    (65537ull + 3ull*4194304ull)

typedef __attribute__((ext_vector_type(8))) short bf16x8;
typedef __attribute__((ext_vector_type(4))) float f32x4;

__device__ __forceinline__ float bf2f(unsigned short h) {
  union { unsigned int u; float f; } v; v.u = ((unsigned int)h) << 16; return v.f;
}
__device__ __forceinline__ unsigned short f2bf(float f) {
  union { float f; unsigned int u; } v; v.f = f;
  unsigned int u = v.u;
  return (unsigned short)((u + 0x7FFFu + ((u >> 16) & 1u)) >> 16);
}
__device__ __forceinline__ ushort4 f2bf4(float4 v) {
  ushort4 o; o.x = f2bf(v.x); o.y = f2bf(v.y); o.z = f2bf(v.z); o.w = f2bf(v.w);
  return o;
}
__device__ __forceinline__ float wsum(float v) {
#pragma unroll
  for (int o = 32; o > 0; o >>= 1) v += __shfl_xor(v, o, 64);
  return v;
}
__device__ __forceinline__ float block_sum(float v, float* red) {
  v = wsum(v);
  int lane = threadIdx.x & 63, wv = threadIdx.x >> 6;
  __syncthreads();
  if (lane == 0) red[wv] = v;
  __syncthreads();
  return red[0] + red[1] + red[2] + red[3];
}
__device__ __forceinline__ float artanh_clip(float x) {
  x = fminf(fmaxf(x, -1.0f + 1e-5f), 1.0f - 1e-5f);
  return 0.5f * (log1pf(x) - log1pf(-x));
}

typedef __attribute__((address_space(1))) const void gas_void;
typedef __attribute__((address_space(3))) void las_void;
__device__ __forceinline__ void gld16(void* l, const void* g) {
  __builtin_amdgcn_global_load_lds((gas_void*)g, (las_void*)l, 16, 0, 0);
}

#define VMCNT(n) asm volatile("s_waitcnt vmcnt(" #n ")" ::: "memory")

// ---------------------------------------------------------------------------
// k_front: fused {p_logmap0 gf-prep} ∪ {mlr precompute} ∪ {fp32->bf16 convert}
// ---------------------------------------------------------------------------
struct Cvt6 {
  const float4* src[6];
  unsigned short* dst[6];
  unsigned int end4[6];   // cumulative float4 counts
};

__device__ __forceinline__ void prep_gf_body(const float* __restrict__ ohyp,
    const float* __restrict__ fhyp, const float* __restrict__ oeuc,
    const float* __restrict__ feuc, unsigned short* __restrict__ gf,
    int b, float* red) {
  int t = threadIdx.x;
  size_t base4 = (size_t)b * (DD / 4);
  float4 xo = ((const float4*)ohyp)[base4 + t];
  float4 xf = ((const float4*)fhyp)[base4 + t];
  float so = xo.x * xo.x + xo.y * xo.y + xo.z * xo.z + xo.w * xo.w;
  float sf = xf.x * xf.x + xf.y * xf.y + xf.z * xf.z + xf.w * xf.w;
  float no2 = block_sum(so, red);
  float nf2 = block_sum(sf, red);
  float no = fmaxf(sqrtf(no2), 1e-15f);
  float nf = fmaxf(sqrtf(nf2), 1e-15f);
  float fo = artanh_clip(SCF * no) / (no * SCF);
  float ff = artanh_clip(SCF * nf) / (nf * SCF);
  size_t g0 = (size_t)b * 4 * (DD / 4);
  float4 e2 = ((const float4*)oeuc)[base4 + t];
  float4 e3 = ((const float4*)feuc)[base4 + t];
  float4 y0 = {xo.x * fo, xo.y * fo, xo.z * fo, xo.w * fo};
  float4 y1 = {xf.x * ff, xf.y * ff, xf.z * ff, xf.w * ff};
  ((ushort4*)gf)[g0 + t]              = f2bf4(y0);
  ((ushort4*)gf)[g0 + DD / 4 + t]     = f2bf4(y1);
  ((ushort4*)gf)[g0 + 2 * DD / 4 + t] = f2bf4(e2);
  ((ushort4*)gf)[g0 + 3 * DD / 4 + t] = f2bf4(e3);
}

__device__ __forceinline__ void mlr_prep_body(const float* __restrict__ a,
    const float* __restrict__ p, float* __restrict__ p_p, float* __restrict__ a_p,
    float* __restrict__ cs, int c, float* red) {
  int t = threadIdx.x;
  size_t base4 = (size_t)c * (DD / 4);
  float4 pv = ((const float4*)p)[base4 + t];
  float4 av = ((const float4*)a)[base4 + t];
  float sp = pv.x * pv.x + pv.y * pv.y + pv.z * pv.z + pv.w * pv.w;
  float sa = av.x * av.x + av.y * av.y + av.z * av.z + av.w * av.w;
  float spa = pv.x * av.x + pv.y * av.y + pv.z * av.z + pv.w * av.w;
  sp = block_sum(sp, red); sa = block_sum(sa, red); spa = block_sum(spa, red);
  float n = fmaxf(sqrtf(sp), 1e-15f);
  float f = tanhf(SCF * n) / (SCF * n);
  float x2 = f * f * sp;
  float conf = 1.0f - CURVF * x2;
  float a_norm = fabsf(conf) * sqrtf(sa);
  float lam = 2.0f / (1.0f - CURVF * x2);
  float kk = lam * a_norm / SCF;
  float xa = -f * conf * spa;
  float4 pp = {pv.x * f, pv.y * f, pv.z * f, pv.w * f};
  float4 ap = {av.x * conf, av.y * conf, av.z * conf, av.w * conf};
  ((float4*)p_p)[base4 + t] = pp;
  ((float4*)a_p)[base4 + t] = ap;
  if (threadIdx.x == 0) {
    cs[c * 5 + 0] = x2; cs[c * 5 + 1] = conf; cs[c * 5 + 2] = a_norm;
    cs[c * 5 + 3] = kk; cs[c * 5 + 4] = xa;
  }
}

__global__ __launch_bounds__(256) void k_front(
    const float* __restrict__ ohyp, const float* __restrict__ fhyp,
    const float* __restrict__ oeuc, const float* __restrict__ feuc,
    unsigned short* __restrict__ gf,
    const float* __restrict__ mlr_a, const float* __restrict__ mlr_p,
    float* __restrict__ p_p, float* __restrict__ a_p, float* __restrict__ cs,
    Cvt6 cv, unsigned int total4) {
  __shared__ float red[4];
  unsigned int blk = blockIdx.x;
  if (blk < BB) {
    prep_gf_body(ohyp, fhyp, oeuc, feuc, gf, (int)blk, red);
    return;
  }
  if (blk < BB + CC) {
    mlr_prep_body(mlr_a, mlr_p, p_p, a_p, cs, (int)(blk - BB), red);
    return;
  }
  unsigned int i = (blk - BB - CC) * 256 + threadIdx.x;
  if (i >= total4) return;
#pragma unroll
  for (int j = 0; j < 6; j++) {
    if (i < cv.end4[j]) {
      unsigned int k = i - (j ? cv.end4[j - 1] : 0u);
      ((ushort4*)cv.dst[j])[k] = f2bf4(cv.src[j][k]);
      return;
    }
  }
}

// ---------------------------------------------------------------------------
// 256x256-tile bf16 GEMM body, C = A(MxK) * Bm(NxK)^T + bias.  [R3-verified:
// 118 us QKV, 874 TF, 0 bank conflicts]
// 8 waves (2Mx4N), BK=32, 4-deep LDS ring (4 x 32KB = 128KB), counted
// vmcnt(8) pipeline, setprio around MFMA clusters.
// XOR involution swizzle: stage from pre-swizzled global column
// lc = (tid&3) ^ ((srow>>1)&3) into LINEAR LDS dest (global_load_lds rule),
// read back at chunk (hi ^ ((fr>>1)&3)). Lanes 0-7 hit 8 distinct bank-quads.
// NOTE (R4/R5): finer 8-phase with per-phase lgkmcnt(0)+sched_barrier fences
// REGRESSED (fences block compiler VALU/MFMA interleave). This is the best
// measured structure (~m97-structure ceiling).
// ---------------------------------------------------------------------------
__device__ __forceinline__ void gemm256_body(
    const unsigned short* __restrict__ A, const unsigned short* __restrict__ Bm,
    const float* __restrict__ bias, void* __restrict__ Cv,
    int N, int K, int bx, int by, int out_bf16,
    unsigned short (*lds)[2][8192]) {
  const long tileM = (long)by * 256;
  const long tileN = (long)bx * 256;
  const int tid = threadIdx.x;
  const int lane = tid & 63;
  const int wv = tid >> 6;       // 0..7
  const int wr = wv >> 2;        // 0..1  (M half)
  const int wc = wv & 3;         // 0..3  (N quarter)
  const int NT = K >> 5;         // K-tiles of 32

  f32x4 acc[8][4];
#pragma unroll
  for (int i = 0; i < 8; i++)
#pragma unroll
    for (int j = 0; j < 4; j++) acc[i][j] = (f32x4){0.f, 0.f, 0.f, 0.f};

  const int srow = tid >> 2;                 // 0..127
  const int lc = (tid & 3) ^ ((srow >> 1) & 3);
  const unsigned short* Ag = A + (tileM + srow) * (long)K + lc * 8;
  const unsigned short* Bg = Bm + (tileN + srow) * (long)K + lc * 8;

  auto stageA = [&](int t) {
    int b = t & 3;
    const unsigned short* s = Ag + t * 32;
    gld16(&lds[b][0][tid * 8], s);
    gld16(&lds[b][0][4096 + tid * 8], s + (long)128 * K);
  };
  auto stageB = [&](int t) {
    int b = t & 3;
    const unsigned short* s = Bg + t * 32;
    gld16(&lds[b][1][tid * 8], s);
    gld16(&lds[b][1][4096 + tid * 8], s + (long)128 * K);
  };

  // prologue: 3 K-tiles in flight; wait only for tile 0 (newest 8 = tiles 1,2)
  stageA(0); stageB(0);
  stageA(1); stageB(1);
  stageA(2); stageB(2);
  VMCNT(8);
  __builtin_amdgcn_s_barrier();
  asm volatile("" ::: "memory");

  const int fr = lane & 15;
  const int hi = lane >> 4;
  const int fko = (hi ^ ((fr >> 1) & 3)) * 8;   // swizzled read chunk

  for (int t = 0; t < NT; ++t) {
    const unsigned short* Ab = &lds[t & 3][0][0];
    const unsigned short* Bb = &lds[t & 3][1][0];
    bf16x8 af[4], bfr[4];
    // ---- phase 1: B frags + A frags 0-3, stage A(t+3), 16 MFMA
#pragma unroll
    for (int j = 0; j < 4; j++)
      bfr[j] = *(const bf16x8*)(Bb + (wc * 64 + j * 16 + fr) * 32 + fko);
#pragma unroll
    for (int i = 0; i < 4; i++)
      af[i] = *(const bf16x8*)(Ab + (wr * 128 + i * 16 + fr) * 32 + fko);
    if (t + 3 < NT) stageA(t + 3);
    __builtin_amdgcn_s_setprio(1);
#pragma unroll
    for (int i = 0; i < 4; i++)
#pragma unroll
      for (int j = 0; j < 4; j++)
        acc[i][j] = __builtin_amdgcn_mfma_f32_16x16x32_bf16(af[i], bfr[j], acc[i][j], 0, 0, 0);
    __builtin_amdgcn_s_setprio(0);
    // ---- phase 2: A frags 4-7 (reuse B frags), stage B(t+3), 16 MFMA
#pragma unroll
    for (int i = 0; i < 4; i++)
      af[i] = *(const bf16x8*)(Ab + (wr * 128 + (i + 4) * 16 + fr) * 32 + fko);
    if (t + 3 < NT) stageB(t + 3);
    __builtin_amdgcn_s_setprio(1);
#pragma unroll
    for (int i = 0; i < 4; i++)
#pragma unroll
      for (int j = 0; j < 4; j++)
        acc[i + 4][j] = __builtin_amdgcn_mfma_f32_16x16x32_bf16(af[i], bfr[j], acc[i + 4][j], 0, 0, 0);
    __builtin_amdgcn_s_setprio(0);
    // ---- boundary: ensure tile t+1 landed (counted vmcnt, never 0 mid-loop)
    if (t + 1 < NT) {
      if (t + 3 < NT)      VMCNT(8);
      else if (t + 2 < NT) VMCNT(4);
      else                 VMCNT(0);
      __builtin_amdgcn_s_barrier();
      asm volatile("" ::: "memory");
    }
  }

  // epilogue
  const int er = hi * 4;
  if (out_bf16) {
#pragma unroll
    for (int i = 0; i < 8; i++)
#pragma unroll
      for (int j = 0; j < 4; j++) {
        long col = tileN + wc * 64 + j * 16 + fr;
        float bv = bias ? bias[col] : 0.f;
#pragma unroll
        for (int r = 0; r < 4; r++) {
          long row = tileM + wr * 128 + i * 16 + er + r;
          ((unsigned short*)Cv)[row * (long)N + col] = f2bf(acc[i][j][r] + bv);
        }
      }
  } else {
#pragma unroll
    for (int i = 0; i < 8; i++)
#pragma unroll
      for (int j = 0; j < 4; j++) {
        long col = tileN + wc * 64 + j * 16 + fr;
        float bv = bias ? bias[col] : 0.f;
#pragma unroll
        for (int r = 0; r < 4; r++) {
          long row = tileM + wr * 128 + i * 16 + er + r;
          ((float*)Cv)[row * (long)N + col] = acc[i][j][r] + bv;
        }
      }
  }
}

// Plain 256² GEMM (used for out-proj)
template <int OUT_BF16>
__global__ __launch_bounds__(512) void k_gemm256(
    const unsigned short* __restrict__ A, const unsigned short* __restrict__ Bm,
    const float* __restrict__ bias, void* __restrict__ Cv,
    int N, int K, int nx) {
  __shared__ unsigned short lds[4][2][8192];
  const int nwg = gridDim.x;
  const int rid = blockIdx.x;
  const int wg = (rid & 7) * (nwg >> 3) + (rid >> 3);  // XCD-contiguous (nwg%8==0)
  gemm256_body(A, Bm, bias, Cv, N, K, wg % nx, wg / nx, OUT_BF16, lds);
}

// Merged dispatch: QKV GEMM (768 wgs, bf16 out) + both loss GEMMs (64 wgs
// each, fp32 out). Loss GEMMs depend only on k_front, so they ride in the
// same dispatch and fill CU slots as QKV blocks retire (896 wgs, %8==0).
__global__ __launch_bounds__(512) void k_gemm_merged(
    const unsigned short* __restrict__ A0, const unsigned short* __restrict__ B0,
    const float* __restrict__ bias0, void* __restrict__ C0, int N0, int K0,
    int nx0, int nwg0,
    const unsigned short* __restrict__ A1, const unsigned short* __restrict__ B1,
    const float* __restrict__ bias1, void* __restrict__ C1,
    const unsigned short* __restrict__ A2, const unsigned short* __restrict__ B2,
    const float* __restrict__ bias2, void* __restrict__ C2,
    int N12, int K12, int nx12, int nwg1) {
  __shared__ unsigned short lds[4][2][8192];
  const int nwg = gridDim.x;
  const int rid = blockIdx.x;
  const int wg = (rid & 7) * (nwg >> 3) + (rid >> 3);  // XCD-contiguous
  if (wg < nwg0) {
    gemm256_body(A0, B0, bias0, C0, N0, K0, wg % nx0, wg / nx0, 1, lds);
  } else if (wg < nwg0 + nwg1) {
    int w = wg - nwg0;
    gemm256_body(A1, B1, bias1, C1, N12, K12, w % nx12, w / nx12, 0, lds);
  } else {
    int w = wg - nwg0 - nwg1;
    gemm256_body(A2, B2, bias2, C2, N12, K12, w % nx12, w / nx12, 0, lds);
  }
}

// ---------------------------------------------------------------------------
// tiny attention: S=4, one block per (b,h); wave qi handles query qi.
// ---------------------------------------------------------------------------
__global__ __launch_bounds__(256) void k_attn(const unsigned short* __restrict__ qkv,
                                              unsigned short* __restrict__ o) {
  int b = blockIdx.x;
  int h = blockIdx.y;
  int lane = threadIdx.x & 63;
  int qi = threadIdx.x >> 6;
  const unsigned short* base = qkv + (size_t)b * 4 * 3072 + h * HD;
  int d = lane * 4;
  float qv[4], kv[4][4], vv[4][4];
  {
    ushort4 q4 = *(const ushort4*)(base + (size_t)qi * 3072 + d);
    qv[0] = bf2f(q4.x); qv[1] = bf2f(q4.y); qv[2] = bf2f(q4.z); qv[3] = bf2f(q4.w);
  }
#pragma unroll
  for (int j = 0; j < 4; j++) {
    ushort4 k4 = *(const ushort4*)(base + (size_t)j * 3072 + 1024 + d);
    ushort4 v4 = *(const ushort4*)(base + (size_t)j * 3072 + 2048 + d);
    kv[j][0] = bf2f(k4.x); kv[j][1] = bf2f(k4.y); kv[j][2] = bf2f(k4.z); kv[j][3] = bf2f(k4.w);
    vv[j][0] = bf2f(v4.x); vv[j][1] = bf2f(v4.y); vv[j][2] = bf2f(v4.z); vv[j][3] = bf2f(v4.w);
  }
  float sc_[4];
#pragma unroll
  for (int j = 0; j < 4; j++) {
    float p = 0.f;
#pragma unroll
    for (int t = 0; t < 4; t++) p += qv[t] * kv[j][t];
    sc_[j] = wsum(p) * (1.0f / 16.0f);
  }
  float mx = fmaxf(fmaxf(sc_[0], sc_[1]), fmaxf(sc_[2], sc_[3]));
  float e[4], den = 0.f;
#pragma unroll
  for (int j = 0; j < 4; j++) { e[j] = expf(sc_[j] - mx); den += e[j]; }
  float inv = 1.0f / den;
  float4 ov = {0.f, 0.f, 0.f, 0.f};
#pragma unroll
  for (int j = 0; j < 4; j++) {
    float w = e[j] * inv;
    ov.x += w * vv[j][0]; ov.y += w * vv[j][1];
    ov.z += w * vv[j][2]; ov.w += w * vv[j][3];
  }
  *(ushort4*)(o + (size_t)(b * 4 + qi) * DD + h * HD + d) = f2bf4(ov);
}

// ---------------------------------------------------------------------------
// k_ln_oxy: layernorm(gf + attn) + split; s<2 additionally l_expmap0 AND the
// fused cone-penalty (oxy) for the paired feature row — the y-vector oxy
// needs is exactly this block's output (y*fmul, still in registers), saving
// k_oxy's dispatch + its 33.5 MB y re-read.
// Pairing: s==0 produces oh  -> oxy which=1 (raw=ffeat vs oh).
//          s==1 produces fh  -> oxy which=0 (raw=ofeat vs fh).
// ---------------------------------------------------------------------------
__global__ __launch_bounds__(256) void k_ln_oxy(const unsigned short* __restrict__ gf,
    const unsigned short* __restrict__ attn, const float* __restrict__ lnw,
    const float* __restrict__ lnb, const float* __restrict__ ofeat,
    const float* __restrict__ ffeat, float* __restrict__ pens,
    float* __restrict__ dout) {
  __shared__ float red[4];
  int r = blockIdx.x;
  int b = r >> 2, s = r & 3;
  int t = threadIdx.x;
  size_t base4 = (size_t)r * (DD / 4);
  ushort4 g4 = ((const ushort4*)gf)[base4 + t];
  ushort4 a4 = ((const ushort4*)attn)[base4 + t];
  float x[4] = {bf2f(g4.x) + bf2f(a4.x), bf2f(g4.y) + bf2f(a4.y),
                bf2f(g4.z) + bf2f(a4.z), bf2f(g4.w) + bf2f(a4.w)};
  float sum = x[0] + x[1] + x[2] + x[3];
  float sq = x[0] * x[0] + x[1] * x[1] + x[2] * x[2] + x[3] * x[3];
  sum = block_sum(sum, red);
  sq  = block_sum(sq, red);
  float mu = sum * (1.0f / (float)DD);
  float var = sq * (1.0f / (float)DD) - mu * mu;
  float inv = rsqrtf(var + 1e-5f);
  float4 w4 = ((const float4*)lnw)[t];
  float4 b4 = ((const float4*)lnb)[t];
  float y[4];
  y[0] = (x[0] - mu) * inv * w4.x + b4.x;
  y[1] = (x[1] - mu) * inv * w4.y + b4.y;
  y[2] = (x[2] - mu) * inv * w4.z + b4.z;
  y[3] = (x[3] - mu) * inv * w4.w + b4.w;
  float fmul = 1.0f;
  if (s < 2) {
    float n2 = y[0] * y[0] + y[1] * y[1] + y[2] * y[2] + y[3] * y[3];
    n2 = block_sum(n2, red);
    float rc = SCF * sqrtf(n2);
    float si = fminf(fmaxf(rc, EPSF), ASINH_MAXF);
    fmul = sinhf(si) / fmaxf(rc, EPSF);
  }
  size_t offs = (s == 0) ? OFF_OH : (s == 1) ? OFF_FH : (s == 2) ? OFF_OEU : OFF_FEU;
  float4* outp = (float4*)(dout + offs + (size_t)b * DD);
  float4 o4 = {y[0] * fmul, y[1] * fmul, y[2] * fmul, y[3] * fmul};
  outp[t] = o4;

  if (s < 2) {
    // fused oxy: raw = pre-expmap loss-GEMM feature row; y = o4 (in regs)
    const float* raw = (s == 0) ? ffeat : ofeat;
    float4 rv = ((const float4*)(raw + (size_t)b * DD))[t];
    float sxx = rv.x * rv.x + rv.y * rv.y + rv.z * rv.z + rv.w * rv.w;
    float sxy = rv.x * o4.x + rv.y * o4.y + rv.z * o4.z + rv.w * o4.w;
    float syy = o4.x * o4.x + o4.y * o4.y + o4.z * o4.z + o4.w * o4.w;
    sxx = block_sum(sxx, red);
    sxy = block_sum(sxy, red);
    syy = block_sum(syy, red);
    if (t == 0) {
      float nraw = sqrtf(sxx);
      float rc2 = SCF * nraw;
      float si2 = fminf(fmaxf(rc2, EPSF), ASINH_MAXF);
      float f = sinhf(si2) / fmaxf(rc2, EPSF);
      float x2 = f * f * sxx;
      float xy = f * sxy;
      float y2 = syy;
      float nx = f * nraw;
      float xt = sqrtf(1.0f / CURVF + x2);
      float yt = sqrtf(1.0f / CURVF + y2);
      float c_xyl = CURVF * (xy - xt * yt);
      float num = yt + c_xyl * xt;
      float den = sqrtf(fmaxf(c_xyl * c_xyl - 1.0f, EPSF));
      float ai = num / (nx * den + EPSF);
      ai = fminf(fmaxf(ai, -1.0f + EPSF), 1.0f - EPSF);
      float ang = acosf(ai);
      float asi = 0.2f / (nx * SCF + EPSF);
      asi = fminf(fmaxf(asi, -1.0f + EPSF), 1.0f - EPSF);
      float ap = asinf(asi);
      int which = (s == 0) ? 1 : 0;
      pens[(size_t)which * BB + b] = fmaxf(ang - ap, 0.0f);
    }
  }
}

// ---------------------------------------------------------------------------
// k_back: fused {MLR logits} ∪ {loss finalize}.
// Grid: [0, BB) -> mlr_logits row b;  BB -> finalize_loss.
// ---------------------------------------------------------------------------
__global__ __launch_bounds__(256) void k_back(const float* __restrict__ oh,
    const float* __restrict__ p_p, const float* __restrict__ a_p,
    const float* __restrict__ cs, float* __restrict__ logits,
    const float* __restrict__ pens, const int* __restrict__ mask,
    float* __restrict__ dout) {
  __shared__ float row[DD];
  __shared__ float dots[CC][2];
  __shared__ float s_n2;
  __shared__ float red[4];
  int blk = blockIdx.x;
  int lane = threadIdx.x & 63, wv = threadIdx.x >> 6;

  if (blk == BB) {
    // ---- finalize_loss
    float s0 = 0.f, s1 = 0.f, cnt = 0.f;
    for (int i = threadIdx.x; i < BB; i += 256) {
      s0 += pens[i];
      float m = (float)mask[i];
      s1 += pens[BB + i] * m;
      cnt += m;
    }
    s0 = block_sum(s0, red);
    s1 = block_sum(s1, red);
    cnt = block_sum(cnt, red);
    if (threadIdx.x == 0) {
      float order_loss = s0 / (float)BB;
      float fam = (cnt > 0.f) ? s1 / fmaxf(cnt, 1.0f) : 0.0f;
      dout[OFF_LOSS] = order_loss + fam;
    }
    return;
  }

  // ---- mlr_logits
  int b = blk;
  const float* src = oh + (size_t)b * DD;
#pragma unroll
  for (int k = 0; k < 4; k++)
    row[threadIdx.x + 256 * k] = src[threadIdx.x + 256 * k];
  __syncthreads();
  if (wv == 0) {
    float n2p = 0.f;
#pragma unroll
    for (int k = 0; k < 4; k++) {
      float4 v = ((const float4*)row)[lane + 64 * k];
      n2p += v.x * v.x + v.y * v.y + v.z * v.z + v.w * v.w;
    }
    n2p = wsum(n2p);
    if (lane == 0) s_n2 = n2p;
  }
#pragma unroll
  for (int ccc = 0; ccc < 4; ccc++) {
    int c = wv * 4 + ccc;
    const float4* pp4 = (const float4*)(p_p + (size_t)c * DD);
    const float4* ap4 = (const float4*)(a_p + (size_t)c * DD);
    float dp = 0.f, da = 0.f;
#pragma unroll
    for (int k = 0; k < 4; k++) {
      int d4 = lane + 64 * k;
      float4 v = ((const float4*)row)[d4];
      float4 p4 = pp4[d4];
      float4 a4 = ap4[d4];
      dp += p4.x * v.x + p4.y * v.y + p4.z * v.z + p4.w * v.w;
      da += a4.x * v.x + a4.y * v.y + a4.z * v.z + a4.w * v.w;
    }
    dp = wsum(dp); da = wsum(da);
    if (lane == 0) { dots[c][0] = dp; dots[c][1] = da; }
  }
  __syncthreads();
  if (threadIdx.x < CC) {
    int c = threadIdx.x;
    float n2 = s_n2;
    float n1 = sqrtf(n2);
    float rc = SCF * n1;
    float g = asinhf(rc) / fmaxf(rc, EPSF);
    float nu = fmaxf(n1 * g, 1e-15f);
    float fac = tanhf(SCF * nu) / (SCF * nu);
    float s = g * fac;
    float ny = fmaxf(n1 * s, 1e-15f);
    float maxn = (1.0f - 0.004f) / SCF;
    if (ny > maxn) s *= maxn / ny;
    float y2 = s * s * n2;
    float py = s * dots[c][0];
    float ay = s * dots[c][1];
    float x2 = cs[c * 5 + 0], conf = cs[c * 5 + 1], a_norm = cs[c * 5 + 2];
    float kk = cs[c * 5 + 3], xa = cs[c * 5 + 4];
    float xy = -py;
    float A = 1.f + 2.f * CURVF * xy + CURVF * y2;
    float den0 = 1.f + 2.f * CURVF * xy + CURVF * CURVF * x2 * y2;
    float d = den0 + 1e-5f;
    float num = 2.f * SCF * (A * xa + conf * ay) / d;
    float mob2 = (A * A * x2 + 2.f * A * conf * xy + conf * conf * y2) / (d * d);
    float denl = a_norm * (1.f - CURVF * mob2);
    logits[(size_t)b * CC + c] = kk * asinhf(num / denl);
  }
}

// ---------------------------------------------------------------------------
// Launcher — 6 dispatches:
//   k_front -> k_gemm_merged(QKV+loss GEMMs) -> k_attn -> k_gemm256(out-proj)
//   -> k_ln_oxy -> k_back
// ---------------------------------------------------------------------------
extern "C" void kernel_launch(void* const* d_in, const int* in_sizes, int n_in,
                              void* d_out, int out_size, void* d_ws, size_t ws_size,
                              hipStream_t stream) {
  const float* order_hyp  = (const float*)d_in[0];
  const float* family_hyp = (const float*)d_in[1];
  const float* order_euc  = (const float*)d_in[2];
  const float* family_euc = (const float*)d_in[3];
  const float* order      = (const float*)d_in[4];
  const float* family     = (const float*)d_in[5];
  const int*   mask       = (const int*)d_in[6];
  const float* in_proj_w  = (const float*)d_in[7];
  const float* in_proj_b  = (const float*)d_in[8];
  const float* out_proj_w = (const float*)d_in[9];
  const float* out_proj_b = (const float*)d_in[10];
  const float* ln_w       = (const float*)d_in[11];
  const float* ln_b       = (const float*)d_in[12];
  const float* to_w       = (const float*)d_in[13];
  const float* to_b       = (const float*)d_in[14];
  const float* tf_w       = (const float*)d_in[15];
  const float* tf_b       = (const float*)d_in[16];
  const float* mlr_a      = (const float*)d_in[17];
  const float* mlr_p      = (const float*)d_in[18];
  float* dout = (float*)d_out;

  char* w = (char*)d_ws;
  size_t off = 0;
  auto take = [&](size_t n) { char* p = w + off; off += (n + 255) & ~(size_t)255; return p; };
  unsigned short* gf_bf   = (unsigned short*)take((size_t)M1 * DD * 2);
  unsigned short* region2 = (unsigned short*)take((size_t)M1 * 3 * DD * 2);
  unsigned short* o_bf    = (unsigned short*)take((size_t)M1 * DD * 2);
  unsigned short* win_bf  = (unsigned short*)take((size_t)3 * DD * DD * 2);
  unsigned short* wout_bf = (unsigned short*)take((size_t)DD * DD * 2);
  unsigned short* tow_bf  = (unsigned short*)take((size_t)DD * TT * 2);
  unsigned short* tfw_bf  = (unsigned short*)take((size_t)DD * TT * 2);
  unsigned short* ord_bf  = (unsigned short*)take((size_t)BB * TT * 2);
  unsigned short* fam_bf  = (unsigned short*)take((size_t)BB * TT * 2);
  float* p_p   = (float*)take((size_t)CC * DD * 4);
  float* a_p   = (float*)take((size_t)CC * DD * 4);
  float* cs    = (float*)take(CC * 5 * 4);
  float* pens  = (float*)take((size_t)2 * BB * 4);
  float* ofeat = (float*)take((size_t)BB * DD * 4);
  float* ffeat = (float*)take((size_t)BB * DD * 4);

  unsigned short* qkv     = region2;
  unsigned short* attn_bf = region2;

  // ---- fused front: prep_gf + mlr_prep + bf16 converts
  Cvt6 cv;
  cv.src[0] = (const float4*)in_proj_w;  cv.dst[0] = win_bf;
  cv.src[1] = (const float4*)out_proj_w; cv.dst[1] = wout_bf;
  cv.src[2] = (const float4*)to_w;       cv.dst[2] = tow_bf;
  cv.src[3] = (const float4*)tf_w;       cv.dst[3] = tfw_bf;
  cv.src[4] = (const float4*)order;      cv.dst[4] = ord_bf;
  cv.src[5] = (const float4*)family;     cv.dst[5] = fam_bf;
  unsigned int n4[6] = {3u * DD * DD / 4, DD * DD / 4, DD * TT / 4, DD * TT / 4,
                        BB * TT / 4, BB * TT / 4};
  unsigned int acc4 = 0;
  for (int j = 0; j < 6; j++) { acc4 += n4[j]; cv.end4[j] = acc4; }
  unsigned int cvtBlocks = (acc4 + 255) / 256;
  k_front<<<BB + CC + cvtBlocks, 256, 0, stream>>>(
      order_hyp, family_hyp, order_euc, family_euc, gf_bf,
      mlr_a, mlr_p, p_p, a_p, cs, cv, acc4);

  // ---- merged GEMM dispatch:
  //   wg [0,768):    qkv = gf @ in_proj_w^T + b   (16384 x 3072, K=1024, bf16)
  //   wg [768,832):  ofeat = ord @ to_w^T + to_b  ( 4096 x 1024, K=768, f32)
  //   wg [832,896):  ffeat = fam @ tf_w^T + tf_b  ( 4096 x 1024, K=768, f32)
  {
    int nx0 = 3 * DD / 256, ny0 = M1 / 256;   // 12 x 64 = 768
    int nwg0 = nx0 * ny0;
    int nx12 = DD / 256, ny12 = BB / 256;     // 4 x 16 = 64 each
    int nwg1 = nx12 * ny12;
    int total = nwg0 + 2 * nwg1;              // 896, %8 == 0
    k_gemm_merged<<<total, 512, 0, stream>>>(
        gf_bf, win_bf, in_proj_b, qkv, 3 * DD, DD, nx0, nwg0,
        ord_bf, tow_bf, to_b, ofeat,
        fam_bf, tfw_bf, tf_b, ffeat,
        DD, TT, nx12, nwg1);
  }

  k_attn<<<dim3(BB, HH), 256, 0, stream>>>(qkv, o_bf);

  // attn = o @ out_proj_w^T + b   (16384 x 1024, K=1024)
  {
    int nx = DD / 256, ny = M1 / 256;         // 4 x 64 = 256 wgs
    k_gemm256<1><<<nx * ny, 512, 0, stream>>>(
        o_bf, wout_bf, out_proj_b, attn_bf, DD, DD, nx);
  }

  // layernorm + split + fused cone penalties
  k_ln_oxy<<<M1, 256, 0, stream>>>(gf_bf, attn_bf, ln_w, ln_b,
                                   ofeat, ffeat, pens, dout);

  // ---- fused back: mlr_logits + finalize_loss
  k_back<<<BB + 1, 256, 0, stream>>>(dout + OFF_OH, p_p, a_p, cs,
                                     dout + OFF_LOGITS, pens, mask, dout);

  (void)in_sizes; (void)n_in; (void)out_size; (void)ws_size;
}